// Round 1
// baseline (1604.733 us; speedup 1.0000x reference)
//
#include <hip/hip_runtime.h>
#include <cmath>

#define HID 64

// ---------------- utility ----------------

__device__ inline void atomicMaxF(float* addr, float val) {
    unsigned int* ua = (unsigned int*)addr;
    unsigned int old = *ua;
    while (true) {
        float f = __uint_as_float(old);
        if (f >= val) break;
        unsigned int assumed = old;
        old = atomicCAS(ua, assumed, __float_as_uint(val));
        if (old == assumed) break;
    }
}

__global__ void fill_f32(float* __restrict__ p, float v, long n) {
    long i = (long)blockIdx.x * blockDim.x + threadIdx.x;
    long stride = (long)gridDim.x * blockDim.x;
    for (; i < n; i += stride) p[i] = v;
}

// ---------------- SGEMM: C[M,N] = A[M,K] @ B[K,N] (row-major) ----------------
// 64x64 tile, BK=16, 256 threads, 4x4 microtile.
__global__ __launch_bounds__(256) void sgemm64(const float* __restrict__ A,
                                               const float* __restrict__ B,
                                               float* __restrict__ C,
                                               int M, int N, int K) {
    const int bm = blockIdx.x * 64;
    const int bn = blockIdx.y * 64;
    const int tid = threadIdx.x;
    const int tx = tid & 15;   // 0..15 col group
    const int ty = tid >> 4;   // 0..15 row group
    __shared__ float As[16][65];
    __shared__ float Bs[16][65];
    float acc[4][4] = {};
    for (int k0 = 0; k0 < K; k0 += 16) {
        #pragma unroll
        for (int i = 0; i < 4; ++i) {
            int idx = tid + i * 256;     // 0..1023
            int m = idx >> 4;            // 0..63
            int k = idx & 15;
            int gm = bm + m;
            float v = 0.f;
            if (gm < M) v = A[(size_t)gm * K + k0 + k];
            As[k][m] = v;
        }
        #pragma unroll
        for (int i = 0; i < 4; ++i) {
            int idx = tid + i * 256;
            int k = idx >> 6;            // 0..15
            int n = idx & 63;
            float v = 0.f;
            if (bn + n < N) v = B[(size_t)(k0 + k) * N + bn + n];
            Bs[k][n] = v;
        }
        __syncthreads();
        #pragma unroll
        for (int k = 0; k < 16; ++k) {
            float a[4], b[4];
            #pragma unroll
            for (int i = 0; i < 4; ++i) a[i] = As[k][ty * 4 + i];
            #pragma unroll
            for (int j = 0; j < 4; ++j) b[j] = Bs[k][tx * 4 + j];
            #pragma unroll
            for (int i = 0; i < 4; ++i)
                #pragma unroll
                for (int j = 0; j < 4; ++j)
                    acc[i][j] += a[i] * b[j];
        }
        __syncthreads();
    }
    #pragma unroll
    for (int i = 0; i < 4; ++i) {
        int gm = bm + ty * 4 + i;
        if (gm >= M) continue;
        #pragma unroll
        for (int j = 0; j < 4; ++j) {
            int gn = bn + tx * 4 + j;
            if (gn < N) C[(size_t)gm * N + gn] = acc[i][j];
        }
    }
}

// ---------------- per-node alpha dot products ----------------
// block = 256 threads; handles 256/(H*64) nodes; head groups align to waves.
template<int H>
__global__ __launch_bounds__(256) void alpha_kernel(const float* __restrict__ h,
                                                    const float* __restrict__ a_src,
                                                    const float* __restrict__ a_dst,
                                                    float* __restrict__ os,
                                                    float* __restrict__ od, int N) {
    const int F = H * HID;
    const int NPB = 256 / F;
    int t = threadIdx.x;
    int ln = t / F;
    int tt = t - ln * F;
    int n = blockIdx.x * NPB + ln;
    if (n >= N) return;
    float hv = h[(size_t)n * F + tt];
    float s = hv * a_src[tt];
    float d = hv * a_dst[tt];
    #pragma unroll
    for (int off = 32; off > 0; off >>= 1) {
        s += __shfl_down(s, off, 64);
        d += __shfl_down(d, off, 64);
    }
    if ((t & 63) == 0) {
        int head = tt >> 6;
        os[(size_t)n * H + head] = s;
        od[(size_t)n * H + head] = d;
    }
}

// ---------------- edge passes ----------------
template<int H>
__global__ void edge_max_k(const int* __restrict__ ei, int E, int N,
                           const float* __restrict__ as, const float* __restrict__ ad,
                           float* __restrict__ m) {
    int e = blockIdx.x * blockDim.x + threadIdx.x;
    int T = E + N;
    if (e >= T) return;
    int s, d;
    if (e < E) { s = ei[e]; d = ei[E + e]; } else { s = e - E; d = s; }
    #pragma unroll
    for (int h = 0; h < H; ++h) {
        float v = as[s * H + h] + ad[d * H + h];
        v = v > 0.f ? v : 0.2f * v;
        atomicMaxF(&m[d * H + h], v);
    }
}

template<int H>
__global__ void edge_denom_k(const int* __restrict__ ei, int E, int N,
                             const float* __restrict__ as, const float* __restrict__ ad,
                             const float* __restrict__ m, float* __restrict__ den) {
    int e = blockIdx.x * blockDim.x + threadIdx.x;
    int T = E + N;
    if (e >= T) return;
    int s, d;
    if (e < E) { s = ei[e]; d = ei[E + e]; } else { s = e - E; d = s; }
    #pragma unroll
    for (int h = 0; h < H; ++h) {
        float v = as[s * H + h] + ad[d * H + h];
        v = v > 0.f ? v : 0.2f * v;
        atomicAdd(&den[d * H + h], expf(v - m[d * H + h]));
    }
}

// one block per edge, F threads; recompute weight, scatter-add row.
template<int H>
__global__ void aggregate_k(const int* __restrict__ ei, int E, int N,
                            const float* __restrict__ h,
                            const float* __restrict__ as, const float* __restrict__ ad,
                            const float* __restrict__ m, const float* __restrict__ den,
                            float* __restrict__ out) {
    const int F = H * HID;
    int e = blockIdx.x;
    int t = threadIdx.x;
    int s, d;
    if (e < E) { s = ei[e]; d = ei[E + e]; } else { s = e - E; d = s; }
    int head = t >> 6;
    float v = as[s * H + head] + ad[d * H + head];
    v = v > 0.f ? v : 0.2f * v;
    float w = expf(v - m[d * H + head]) / (den[d * H + head] + 1e-16f);
    atomicAdd(&out[(size_t)d * F + t], h[(size_t)s * F + t] * w);
}

__global__ void bias_act_k(float* __restrict__ x, const float* __restrict__ b,
                           long total, int Fmask, int relu) {
    long i = (long)blockIdx.x * blockDim.x + threadIdx.x;
    long stride = (long)gridDim.x * blockDim.x;
    for (; i < total; i += stride) {
        float v = x[i] + b[(int)(i & Fmask)];
        if (relu) v = v > 0.f ? v : 0.f;
        x[i] = v;
    }
}

// ---------------- pooling ----------------
__global__ void pool_k(const float* __restrict__ h, const int* __restrict__ batch,
                       float* __restrict__ pool, float* __restrict__ cnt, int N) {
    const int NPB = 128;
    int c = threadIdx.x;  // 64 threads, one channel each
    int start = blockIdx.x * NPB;
    int end = min(start + NPB, N);
    float acc = 0.f;
    float cl = 0.f;
    int cur = -1;
    for (int n = start; n < end; ++n) {
        int b = batch[n];
        if (b != cur) {
            if (cur >= 0) {
                atomicAdd(&pool[cur * HID + c], acc);
                if (c == 0) atomicAdd(&cnt[cur], cl);
            }
            cur = b; acc = 0.f; cl = 0.f;
        }
        acc += h[(size_t)n * HID + c];
        cl += 1.f;
    }
    if (cur >= 0) {
        atomicAdd(&pool[cur * HID + c], acc);
        if (c == 0) atomicAdd(&cnt[cur], cl);
    }
}

__global__ void finalize_k(const float* __restrict__ pool, const float* __restrict__ cnt,
                           float* __restrict__ out) {
    int g = blockIdx.x;
    int c = threadIdx.x;
    out[g * HID + c] = pool[g * HID + c] / fmaxf(cnt[g], 1.f);
}

// ---------------- launch ----------------

extern "C" void kernel_launch(void* const* d_in, const int* in_sizes, int n_in,
                              void* d_out, int out_size, void* d_ws, size_t ws_size,
                              hipStream_t stream) {
    const float* x      = (const float*)d_in[0];
    const int*   ei     = (const int*)d_in[1];
    const int*   batch  = (const int*)d_in[2];
    const float* W1     = (const float*)d_in[3];
    const float* a_src1 = (const float*)d_in[4];
    const float* a_dst1 = (const float*)d_in[5];
    const float* b1     = (const float*)d_in[6];
    const float* W2     = (const float*)d_in[7];
    const float* a_src2 = (const float*)d_in[8];
    const float* a_dst2 = (const float*)d_in[9];
    const float* b2     = (const float*)d_in[10];
    float* out = (float*)d_out;

    const int N = in_sizes[0] / 128;    // 50000
    const int E = in_sizes[1] / 2;      // 800000
    const int IN_FEAT = 128;
    const int F1 = 256;                 // 4 heads * 64
    const int F2 = 64;                  // 1 head * 64
    const int NG = 32;

    // workspace layout (floats)
    float* ws = (float*)d_ws;
    size_t o = 0;
    float* h1    = ws + o; o += (size_t)N * F1;
    float* out1  = ws + o; o += (size_t)N * F1;
    float* h2    = ws + o; o += (size_t)N * F2;
    float* out2  = ws + o; o += (size_t)N * F2;
    float* asrc1 = ws + o; o += (size_t)N * 4;
    float* adst1 = ws + o; o += (size_t)N * 4;
    float* m1    = ws + o; o += (size_t)N * 4;
    float* den1  = ws + o; o += (size_t)N * 4;
    float* asrc2 = ws + o; o += (size_t)N;
    float* adst2 = ws + o; o += (size_t)N;
    float* m2    = ws + o; o += (size_t)N;
    float* den2  = ws + o; o += (size_t)N;
    float* pools = ws + o; o += (size_t)NG * HID;
    float* cnts  = ws + o; o += (size_t)NG;
    (void)ws_size; (void)n_in; (void)out_size;

    const int T = E + N;  // edges incl. self-loops

    // ---- layer 1 ----
    {
        dim3 g((N + 63) / 64, F1 / 64);
        sgemm64<<<g, 256, 0, stream>>>(x, W1, h1, N, F1, IN_FEAT);
    }
    alpha_kernel<4><<<N, 256, 0, stream>>>(h1, a_src1, a_dst1, asrc1, adst1, N);
    fill_f32<<<512, 256, 0, stream>>>(m1, -INFINITY, (long)N * 4);
    fill_f32<<<512, 256, 0, stream>>>(den1, 0.f, (long)N * 4);
    fill_f32<<<2048, 256, 0, stream>>>(out1, 0.f, (long)N * F1);
    edge_max_k<4><<<(T + 255) / 256, 256, 0, stream>>>(ei, E, N, asrc1, adst1, m1);
    edge_denom_k<4><<<(T + 255) / 256, 256, 0, stream>>>(ei, E, N, asrc1, adst1, m1, den1);
    aggregate_k<4><<<T, 256, 0, stream>>>(ei, E, N, h1, asrc1, adst1, m1, den1, out1);
    bias_act_k<<<2048, 256, 0, stream>>>(out1, b1, (long)N * F1, F1 - 1, 1);

    // ---- layer 2 ----
    {
        dim3 g((N + 63) / 64, F2 / 64);
        sgemm64<<<g, 256, 0, stream>>>(out1, W2, h2, N, F2, F1);
    }
    alpha_kernel<1><<<(N + 3) / 4, 256, 0, stream>>>(h2, a_src2, a_dst2, asrc2, adst2, N);
    fill_f32<<<512, 256, 0, stream>>>(m2, -INFINITY, (long)N);
    fill_f32<<<512, 256, 0, stream>>>(den2, 0.f, (long)N);
    fill_f32<<<2048, 256, 0, stream>>>(out2, 0.f, (long)N * F2);
    edge_max_k<1><<<(T + 255) / 256, 256, 0, stream>>>(ei, E, N, asrc2, adst2, m2);
    edge_denom_k<1><<<(T + 255) / 256, 256, 0, stream>>>(ei, E, N, asrc2, adst2, m2, den2);
    aggregate_k<1><<<T, 64, 0, stream>>>(ei, E, N, h2, asrc2, adst2, m2, den2, out2);
    bias_act_k<<<2048, 256, 0, stream>>>(out2, b2, (long)N * F2, F2 - 1, 0);

    // ---- pooling ----
    fill_f32<<<8, 256, 0, stream>>>(pools, 0.f, (long)NG * HID);
    fill_f32<<<1, 32, 0, stream>>>(cnts, 0.f, (long)NG);
    pool_k<<<(N + 127) / 128, 64, 0, stream>>>(out2, batch, pools, cnts, N);
    finalize_k<<<NG, HID, 0, stream>>>(pools, cnts, out);
}

// Round 2
// 701.034 us; speedup vs baseline: 2.2891x; 2.2891x over previous
//
#include <hip/hip_runtime.h>
#include <cmath>

#define HID 64

// ---------------- fills ----------------

__global__ void fill_f32(float* __restrict__ p, float v, long n) {
    long i = (long)blockIdx.x * blockDim.x + threadIdx.x;
    long stride = (long)gridDim.x * blockDim.x;
    for (; i < n; i += stride) p[i] = v;
}

__global__ void fill_i32(int* __restrict__ p, int v, long n) {
    long i = (long)blockIdx.x * blockDim.x + threadIdx.x;
    long stride = (long)gridDim.x * blockDim.x;
    for (; i < n; i += stride) p[i] = v;
}

// ---------------- SGEMM: C[M,N] = A[M,K] @ B[K,N] (row-major) ----------------
__global__ __launch_bounds__(256) void sgemm64(const float* __restrict__ A,
                                               const float* __restrict__ B,
                                               float* __restrict__ C,
                                               int M, int N, int K) {
    const int bm = blockIdx.x * 64;
    const int bn = blockIdx.y * 64;
    const int tid = threadIdx.x;
    const int tx = tid & 15;
    const int ty = tid >> 4;
    __shared__ float As[16][65];
    __shared__ float Bs[16][65];
    float acc[4][4] = {};
    for (int k0 = 0; k0 < K; k0 += 16) {
        #pragma unroll
        for (int i = 0; i < 4; ++i) {
            int idx = tid + i * 256;
            int m = idx >> 4;
            int k = idx & 15;
            int gm = bm + m;
            float v = 0.f;
            if (gm < M) v = A[(size_t)gm * K + k0 + k];
            As[k][m] = v;
        }
        #pragma unroll
        for (int i = 0; i < 4; ++i) {
            int idx = tid + i * 256;
            int k = idx >> 6;
            int n = idx & 63;
            float v = 0.f;
            if (bn + n < N) v = B[(size_t)(k0 + k) * N + bn + n];
            Bs[k][n] = v;
        }
        __syncthreads();
        #pragma unroll
        for (int k = 0; k < 16; ++k) {
            float a[4], b[4];
            #pragma unroll
            for (int i = 0; i < 4; ++i) a[i] = As[k][ty * 4 + i];
            #pragma unroll
            for (int j = 0; j < 4; ++j) b[j] = Bs[k][tx * 4 + j];
            #pragma unroll
            for (int i = 0; i < 4; ++i)
                #pragma unroll
                for (int j = 0; j < 4; ++j)
                    acc[i][j] += a[i] * b[j];
        }
        __syncthreads();
    }
    #pragma unroll
    for (int i = 0; i < 4; ++i) {
        int gm = bm + ty * 4 + i;
        if (gm >= M) continue;
        #pragma unroll
        for (int j = 0; j < 4; ++j) {
            int gn = bn + tx * 4 + j;
            if (gn < N) C[(size_t)gm * N + gn] = acc[i][j];
        }
    }
}

// ---------------- per-node alpha dot products ----------------
template<int H>
__global__ __launch_bounds__(256) void alpha_kernel(const float* __restrict__ h,
                                                    const float* __restrict__ a_src,
                                                    const float* __restrict__ a_dst,
                                                    float* __restrict__ os,
                                                    float* __restrict__ od, int N) {
    const int F = H * HID;
    const int NPB = 256 / F;
    int t = threadIdx.x;
    int ln = t / F;
    int tt = t - ln * F;
    int n = blockIdx.x * NPB + ln;
    if (n >= N) return;
    float hv = h[(size_t)n * F + tt];
    float s = hv * a_src[tt];
    float d = hv * a_dst[tt];
    #pragma unroll
    for (int off = 32; off > 0; off >>= 1) {
        s += __shfl_down(s, off, 64);
        d += __shfl_down(d, off, 64);
    }
    if ((t & 63) == 0) {
        int head = tt >> 6;
        os[(size_t)n * H + head] = s;
        od[(size_t)n * H + head] = d;
    }
}

// ---------------- CSR build (by destination; includes self-loops) ----------------

__global__ void count_k(const int* __restrict__ ei, int E, int N, int* __restrict__ deg) {
    int e = blockIdx.x * blockDim.x + threadIdx.x;
    int T = E + N;
    if (e >= T) return;
    int d = (e < E) ? ei[E + e] : (e - E);
    atomicAdd(&deg[d], 1);
}

// single-block exclusive scan over deg[0..N) -> rowstart[0..N]
__global__ __launch_bounds__(1024) void scan_k(const int* __restrict__ deg,
                                               int* __restrict__ rowstart, int N) {
    __shared__ int sums[1024];
    int t = threadIdx.x;
    int chunk = (N + 1023) >> 10;
    int lo = t * chunk;
    int hi = lo + chunk; if (hi > N) hi = N;
    int s = 0;
    for (int i = lo; i < hi; ++i) s += deg[i];
    sums[t] = s;
    __syncthreads();
    for (int d = 1; d < 1024; d <<= 1) {
        int v = (t >= d) ? sums[t - d] : 0;
        __syncthreads();
        sums[t] += v;
        __syncthreads();
    }
    int off = sums[t] - s;  // exclusive prefix of this thread's chunk
    for (int i = lo; i < hi; ++i) { rowstart[i] = off; off += deg[i]; }
    if (t == 1023) rowstart[N] = sums[1023];
}

__global__ void scatter_k(const int* __restrict__ ei, int E, int N,
                          const int* __restrict__ rowstart, int* __restrict__ cursor,
                          int* __restrict__ srcs) {
    int e = blockIdx.x * blockDim.x + threadIdx.x;
    int T = E + N;
    if (e >= T) return;
    int s, d;
    if (e < E) { s = ei[e]; d = ei[E + e]; } else { s = e - E; d = s; }
    int p = atomicAdd(&cursor[d], 1);
    srcs[rowstart[d] + p] = s;
}

// ---------------- fused per-destination GAT aggregation ----------------
// block = H*64 threads; one block per destination node.
// Phase 1 (per head wave): max + denom via shuffle reduction.
// Phase 2: register-accumulate weighted neighbor rows; single write + bias + act.
template<int H>
__global__ __launch_bounds__(H * 64) void gat_agg_k(const float* __restrict__ h,
                                                    const int* __restrict__ rowstart,
                                                    const int* __restrict__ srcs,
                                                    const float* __restrict__ as,
                                                    const float* __restrict__ ad,
                                                    const float* __restrict__ bias,
                                                    float* __restrict__ out,
                                                    int N, int relu) {
    const int F = H * HID;
    int d = blockIdx.x;
    if (d >= N) return;
    int t = threadIdx.x;
    int head = t >> 6;
    int lane = t & 63;
    int beg = rowstart[d];
    int end = rowstart[d + 1];
    float adv = ad[d * H + head];
    __shared__ float sm[H], sden[H];

    float vmax = -INFINITY;
    for (int i = beg + lane; i < end; i += 64) {
        int s = srcs[i];
        float v = as[s * H + head] + adv;
        v = v > 0.f ? v : 0.2f * v;
        vmax = fmaxf(vmax, v);
    }
    #pragma unroll
    for (int off = 32; off > 0; off >>= 1) vmax = fmaxf(vmax, __shfl_xor(vmax, off, 64));
    float dsum = 0.f;
    for (int i = beg + lane; i < end; i += 64) {
        int s = srcs[i];
        float v = as[s * H + head] + adv;
        v = v > 0.f ? v : 0.2f * v;
        dsum += expf(v - vmax);
    }
    #pragma unroll
    for (int off = 32; off > 0; off >>= 1) dsum += __shfl_xor(dsum, off, 64);
    if (lane == 0) { sm[head] = vmax; sden[head] = dsum; }
    __syncthreads();

    float mh = sm[head];
    float dh = sden[head] + 1e-16f;
    float acc = 0.f;
    for (int i = beg; i < end; ++i) {
        int s = srcs[i];
        float v = as[s * H + head] + adv;
        v = v > 0.f ? v : 0.2f * v;
        float w = expf(v - mh) / dh;
        acc += h[(size_t)s * F + t] * w;
    }
    float o = acc + bias[t];
    if (relu) o = fmaxf(o, 0.f);
    out[(size_t)d * F + t] = o;
}

// ---------------- pooling ----------------
__global__ void pool_k(const float* __restrict__ h, const int* __restrict__ batch,
                       float* __restrict__ pool, float* __restrict__ cnt, int N) {
    const int NPB = 128;
    int c = threadIdx.x;
    int start = blockIdx.x * NPB;
    int end = min(start + NPB, N);
    float acc = 0.f;
    float cl = 0.f;
    int cur = -1;
    for (int n = start; n < end; ++n) {
        int b = batch[n];
        if (b != cur) {
            if (cur >= 0) {
                atomicAdd(&pool[cur * HID + c], acc);
                if (c == 0) atomicAdd(&cnt[cur], cl);
            }
            cur = b; acc = 0.f; cl = 0.f;
        }
        acc += h[(size_t)n * HID + c];
        cl += 1.f;
    }
    if (cur >= 0) {
        atomicAdd(&pool[cur * HID + c], acc);
        if (c == 0) atomicAdd(&cnt[cur], cl);
    }
}

__global__ void finalize_k(const float* __restrict__ pool, const float* __restrict__ cnt,
                           float* __restrict__ out) {
    int g = blockIdx.x;
    int c = threadIdx.x;
    out[g * HID + c] = pool[g * HID + c] / fmaxf(cnt[g], 1.f);
}

// ---------------- launch ----------------

extern "C" void kernel_launch(void* const* d_in, const int* in_sizes, int n_in,
                              void* d_out, int out_size, void* d_ws, size_t ws_size,
                              hipStream_t stream) {
    const float* x      = (const float*)d_in[0];
    const int*   ei     = (const int*)d_in[1];
    const int*   batch  = (const int*)d_in[2];
    const float* W1     = (const float*)d_in[3];
    const float* a_src1 = (const float*)d_in[4];
    const float* a_dst1 = (const float*)d_in[5];
    const float* b1     = (const float*)d_in[6];
    const float* W2     = (const float*)d_in[7];
    const float* a_src2 = (const float*)d_in[8];
    const float* a_dst2 = (const float*)d_in[9];
    const float* b2     = (const float*)d_in[10];
    float* out = (float*)d_out;

    const int N = in_sizes[0] / 128;    // 50000
    const int E = in_sizes[1] / 2;      // 800000
    const int IN_FEAT = 128;
    const int F1 = 256;
    const int F2 = 64;
    const int NG = 32;
    const int T = E + N;

    // ---- workspace layout ----
    float* ws = (float*)d_ws;
    size_t o = 0;
    float* h1    = ws + o; o += (size_t)N * F1;   // 12.8e6 floats (51.2 MB)
    float* out1  = ws + o; o += (size_t)N * F1;
    float* asrc1 = ws + o; o += (size_t)N * 4;
    float* adst1 = ws + o; o += (size_t)N * 4;
    float* asrc2 = ws + o; o += (size_t)N;
    float* adst2 = ws + o; o += (size_t)N;
    float* pools = ws + o; o += (size_t)NG * HID;
    float* cnts  = ws + o; o += (size_t)NG;
    int* ib = (int*)(ws + o);
    size_t io = 0;
    int* deg      = ib + io; io += N;
    int* rowstart = ib + io; io += N + 1;
    int* cursor   = ib + io; io += N;
    int* srcs     = ib + io; io += T;
    // layer-2 buffers reuse h1's region (h1 dead after layer-1 aggregate)
    float* h2   = h1;
    float* out2 = h1 + (size_t)N * F2;
    (void)ws_size; (void)n_in; (void)out_size;

    // ---- CSR build (destination-sorted, includes self-loops) ----
    fill_i32<<<256, 256, 0, stream>>>(deg, 0, N);
    fill_i32<<<256, 256, 0, stream>>>(cursor, 0, N);
    count_k<<<(T + 255) / 256, 256, 0, stream>>>(ei, E, N, deg);
    scan_k<<<1, 1024, 0, stream>>>(deg, rowstart, N);
    scatter_k<<<(T + 255) / 256, 256, 0, stream>>>(ei, E, N, rowstart, cursor, srcs);

    // ---- layer 1 ----
    {
        dim3 g((N + 63) / 64, F1 / 64);
        sgemm64<<<g, 256, 0, stream>>>(x, W1, h1, N, F1, IN_FEAT);
    }
    alpha_kernel<4><<<N, 256, 0, stream>>>(h1, a_src1, a_dst1, asrc1, adst1, N);
    gat_agg_k<4><<<N, 256, 0, stream>>>(h1, rowstart, srcs, asrc1, adst1, b1, out1, N, 1);

    // ---- layer 2 ----
    {
        dim3 g((N + 63) / 64, F2 / 64);
        sgemm64<<<g, 256, 0, stream>>>(out1, W2, h2, N, F2, F1);
    }
    alpha_kernel<1><<<(N + 3) / 4, 256, 0, stream>>>(h2, a_src2, a_dst2, asrc2, adst2, N);
    gat_agg_k<1><<<N, 64, 0, stream>>>(h2, rowstart, srcs, asrc2, adst2, b2, out2, N, 0);

    // ---- pooling ----
    fill_f32<<<8, 256, 0, stream>>>(pools, 0.f, (long)NG * HID);
    fill_f32<<<1, 32, 0, stream>>>(cnts, 0.f, (long)NG);
    pool_k<<<(N + 127) / 128, 64, 0, stream>>>(out2, batch, pools, cnts, N);
    finalize_k<<<NG, HID, 0, stream>>>(pools, cnts, out);
}

// Round 3
// 501.486 us; speedup vs baseline: 3.2000x; 1.3979x over previous
//
#include <hip/hip_runtime.h>
#include <cmath>

#define HID 64

// ---------------- fills ----------------

__global__ void fill_f32(float* __restrict__ p, float v, long n) {
    long i = (long)blockIdx.x * blockDim.x + threadIdx.x;
    long stride = (long)gridDim.x * blockDim.x;
    for (; i < n; i += stride) p[i] = v;
}

__global__ void fill_i32(int* __restrict__ p, int v, long n) {
    long i = (long)blockIdx.x * blockDim.x + threadIdx.x;
    long stride = (long)gridDim.x * blockDim.x;
    for (; i < n; i += stride) p[i] = v;
}

// ---------------- SGEMM: C[M,N] = A[M,K] @ B[K,N] (row-major) ----------------
// 128 x (NQ*64) tile, BK=16, 256 threads, 8x8 microtile as 2xNQ quadrants of 4x4.
template<int NQ>
__global__ __launch_bounds__(256) void sgemm_big(const float* __restrict__ A,
                                                 const float* __restrict__ B,
                                                 float* __restrict__ C,
                                                 int M, int N, int K) {
    const int BN = NQ * 64;
    const int bm = blockIdx.x * 128;
    const int bn = blockIdx.y * BN;
    const int tid = threadIdx.x;
    const int tx = tid & 15;
    const int ty = tid >> 4;
    __shared__ float As[16][128];
    __shared__ float Bs[16][NQ * 64];
    float acc[2][NQ][4][4] = {};

    for (int k0 = 0; k0 < K; k0 += 16) {
        // A: 128 rows x 16 k -> As[k][m] (transposed store)
        #pragma unroll
        for (int it = 0; it < 2; ++it) {
            int r = (tid >> 2) + it * 64;
            int kg = (tid & 3) * 4;
            int gm = bm + r;
            float4 v = make_float4(0.f, 0.f, 0.f, 0.f);
            if (gm < M) v = *(const float4*)&A[(size_t)gm * K + k0 + kg];
            As[kg + 0][r] = v.x; As[kg + 1][r] = v.y;
            As[kg + 2][r] = v.z; As[kg + 3][r] = v.w;
        }
        // B: 16 k x BN (direct float4 store)
        #pragma unroll
        for (int it = 0; it < NQ; ++it) {
            int k = tid >> 4;
            int c = (tid & 15) * 4 + it * 64;
            float4 v = make_float4(0.f, 0.f, 0.f, 0.f);
            if (bn + c < N) v = *(const float4*)&B[(size_t)(k0 + k) * N + bn + c];
            *(float4*)&Bs[k][c] = v;
        }
        __syncthreads();
        #pragma unroll
        for (int k = 0; k < 16; ++k) {
            float a[2][4], b[NQ][4];
            #pragma unroll
            for (int q = 0; q < 2; ++q)
                *(float4*)a[q] = *(const float4*)&As[k][ty * 4 + q * 64];
            #pragma unroll
            for (int q = 0; q < NQ; ++q)
                *(float4*)b[q] = *(const float4*)&Bs[k][tx * 4 + q * 64];
            #pragma unroll
            for (int qi = 0; qi < 2; ++qi)
                #pragma unroll
                for (int qj = 0; qj < NQ; ++qj)
                    #pragma unroll
                    for (int i = 0; i < 4; ++i)
                        #pragma unroll
                        for (int j = 0; j < 4; ++j)
                            acc[qi][qj][i][j] += a[qi][i] * b[qj][j];
        }
        __syncthreads();
    }
    #pragma unroll
    for (int qi = 0; qi < 2; ++qi)
        #pragma unroll
        for (int i = 0; i < 4; ++i) {
            int gm = bm + qi * 64 + ty * 4 + i;
            if (gm >= M) continue;
            #pragma unroll
            for (int qj = 0; qj < NQ; ++qj) {
                int gn = bn + qj * 64 + tx * 4;
                if (gn < N) {
                    float4 v = make_float4(acc[qi][qj][i][0], acc[qi][qj][i][1],
                                           acc[qi][qj][i][2], acc[qi][qj][i][3]);
                    *(float4*)&C[(size_t)gm * N + gn] = v;
                }
            }
        }
}

// ---------------- per-node alpha dot products ----------------
template<int H>
__global__ __launch_bounds__(256) void alpha_kernel(const float* __restrict__ h,
                                                    const float* __restrict__ a_src,
                                                    const float* __restrict__ a_dst,
                                                    float* __restrict__ os,
                                                    float* __restrict__ od, int N) {
    const int F = H * HID;
    const int NPB = 256 / F;
    int t = threadIdx.x;
    int ln = t / F;
    int tt = t - ln * F;
    int n = blockIdx.x * NPB + ln;
    if (n >= N) return;
    float hv = h[(size_t)n * F + tt];
    float s = hv * a_src[tt];
    float d = hv * a_dst[tt];
    #pragma unroll
    for (int off = 32; off > 0; off >>= 1) {
        s += __shfl_down(s, off, 64);
        d += __shfl_down(d, off, 64);
    }
    if ((t & 63) == 0) {
        int head = tt >> 6;
        os[(size_t)n * H + head] = s;
        od[(size_t)n * H + head] = d;
    }
}

// ---------------- CSR build (by destination; includes self-loops) ----------------

__global__ void count_k(const int* __restrict__ ei, int E, int N, int* __restrict__ deg) {
    int e = blockIdx.x * blockDim.x + threadIdx.x;
    int T = E + N;
    if (e >= T) return;
    int d = (e < E) ? ei[E + e] : (e - E);
    atomicAdd(&deg[d], 1);
}

__global__ __launch_bounds__(1024) void scan_k(const int* __restrict__ deg,
                                               int* __restrict__ rowstart, int N) {
    __shared__ int sums[1024];
    int t = threadIdx.x;
    int chunk = (N + 1023) >> 10;
    int lo = t * chunk;
    int hi = lo + chunk; if (hi > N) hi = N;
    if (lo > N) lo = N;
    int s = 0;
    for (int i = lo; i < hi; ++i) s += deg[i];
    sums[t] = s;
    __syncthreads();
    for (int d = 1; d < 1024; d <<= 1) {
        int v = (t >= d) ? sums[t - d] : 0;
        __syncthreads();
        sums[t] += v;
        __syncthreads();
    }
    int off = sums[t] - s;
    for (int i = lo; i < hi; ++i) { rowstart[i] = off; off += deg[i]; }
    if (t == 1023) rowstart[N] = sums[1023];
}

__global__ void scatter_k(const int* __restrict__ ei, int E, int N,
                          const int* __restrict__ rowstart, int* __restrict__ cursor,
                          int* __restrict__ srcs) {
    int e = blockIdx.x * blockDim.x + threadIdx.x;
    int T = E + N;
    if (e >= T) return;
    int s, d;
    if (e < E) { s = ei[e]; d = ei[E + e]; } else { s = e - E; d = s; }
    int p = atomicAdd(&cursor[d], 1);
    srcs[rowstart[d] + p] = s;
}

// ---------------- fused per-destination GAT aggregation ----------------
// block = H*64 threads, one block per destination node.
// Weights computed once per edge (lane-parallel) and cached in LDS;
// accumulation loop is then 1 gather + 1 FMA per edge per lane.
#define MAXD 128
template<int H>
__global__ __launch_bounds__(H * 64) void gat_agg_k(const float* __restrict__ h,
                                                    const int* __restrict__ rowstart,
                                                    const int* __restrict__ srcs,
                                                    const float* __restrict__ as,
                                                    const float* __restrict__ ad,
                                                    const float* __restrict__ bias,
                                                    float* __restrict__ out,
                                                    int N, int relu) {
    const int F = H * HID;
    int d = blockIdx.x;
    if (d >= N) return;
    int t = threadIdx.x;
    int head = t >> 6;
    int lane = t & 63;
    int beg = rowstart[d];
    int deg = rowstart[d + 1] - beg;
    int dcap = deg < MAXD ? deg : MAXD;

    __shared__ int ssrc[MAXD];
    __shared__ float sw[MAXD][H];

    for (int i = t; i < dcap; i += H * 64) ssrc[i] = srcs[beg + i];
    __syncthreads();

    float adv = ad[d * H + head];

    // pass A: logits + max
    float vmax = -INFINITY;
    for (int i = lane; i < deg; i += 64) {
        int s = (i < MAXD) ? ssrc[i] : srcs[beg + i];
        float v = as[s * H + head] + adv;
        v = v > 0.f ? v : 0.2f * v;
        if (i < MAXD) sw[i][head] = v;
        vmax = fmaxf(vmax, v);
    }
    #pragma unroll
    for (int off = 32; off > 0; off >>= 1) vmax = fmaxf(vmax, __shfl_xor(vmax, off, 64));

    // pass B: exp + sum
    float dsum = 0.f;
    for (int i = lane; i < deg; i += 64) {
        float v;
        if (i < MAXD) v = sw[i][head];
        else {
            int s = srcs[beg + i];
            v = as[s * H + head] + adv;
            v = v > 0.f ? v : 0.2f * v;
        }
        float e = __expf(v - vmax);
        if (i < MAXD) sw[i][head] = e;
        dsum += e;
    }
    #pragma unroll
    for (int off = 32; off > 0; off >>= 1) dsum += __shfl_xor(dsum, off, 64);
    float rden = 1.f / (dsum + 1e-16f);

    // pass C: normalize cached weights (per-head wave owns sw[*][head])
    for (int i = lane; i < dcap; i += 64) sw[i][head] *= rden;

    // accumulate (sw/ssrc written by own wave or before barrier)
    float acc = 0.f;
    int i = 0;
    for (; i + 4 <= dcap; i += 4) {
        int s0 = ssrc[i], s1 = ssrc[i + 1], s2 = ssrc[i + 2], s3 = ssrc[i + 3];
        float w0 = sw[i][head], w1 = sw[i + 1][head];
        float w2 = sw[i + 2][head], w3 = sw[i + 3][head];
        float g0 = h[(size_t)s0 * F + t];
        float g1 = h[(size_t)s1 * F + t];
        float g2 = h[(size_t)s2 * F + t];
        float g3 = h[(size_t)s3 * F + t];
        acc += g0 * w0 + g1 * w1 + g2 * w2 + g3 * w3;
    }
    for (; i < dcap; ++i) acc += h[(size_t)ssrc[i] * F + t] * sw[i][head];
    // rare fallback: degree beyond LDS cache
    for (int j = MAXD; j < deg; ++j) {
        int s = srcs[beg + j];
        float v = as[s * H + head] + adv;
        v = v > 0.f ? v : 0.2f * v;
        acc += h[(size_t)s * F + t] * (__expf(v - vmax) * rden);
    }

    float o = acc + bias[t];
    if (relu) o = fmaxf(o, 0.f);
    out[(size_t)d * F + t] = o;
}

// ---------------- pooling ----------------
__global__ void pool_k(const float* __restrict__ h, const int* __restrict__ batch,
                       float* __restrict__ pool, float* __restrict__ cnt, int N) {
    const int NPB = 128;
    int c = threadIdx.x;
    int start = blockIdx.x * NPB;
    int end = min(start + NPB, N);
    float acc = 0.f;
    float cl = 0.f;
    int cur = -1;
    for (int n = start; n < end; ++n) {
        int b = batch[n];
        if (b != cur) {
            if (cur >= 0) {
                atomicAdd(&pool[cur * HID + c], acc);
                if (c == 0) atomicAdd(&cnt[cur], cl);
            }
            cur = b; acc = 0.f; cl = 0.f;
        }
        acc += h[(size_t)n * HID + c];
        cl += 1.f;
    }
    if (cur >= 0) {
        atomicAdd(&pool[cur * HID + c], acc);
        if (c == 0) atomicAdd(&cnt[cur], cl);
    }
}

__global__ void finalize_k(const float* __restrict__ pool, const float* __restrict__ cnt,
                           float* __restrict__ out) {
    int g = blockIdx.x;
    int c = threadIdx.x;
    out[g * HID + c] = pool[g * HID + c] / fmaxf(cnt[g], 1.f);
}

// ---------------- launch ----------------

extern "C" void kernel_launch(void* const* d_in, const int* in_sizes, int n_in,
                              void* d_out, int out_size, void* d_ws, size_t ws_size,
                              hipStream_t stream) {
    const float* x      = (const float*)d_in[0];
    const int*   ei     = (const int*)d_in[1];
    const int*   batch  = (const int*)d_in[2];
    const float* W1     = (const float*)d_in[3];
    const float* a_src1 = (const float*)d_in[4];
    const float* a_dst1 = (const float*)d_in[5];
    const float* b1     = (const float*)d_in[6];
    const float* W2     = (const float*)d_in[7];
    const float* a_src2 = (const float*)d_in[8];
    const float* a_dst2 = (const float*)d_in[9];
    const float* b2     = (const float*)d_in[10];
    float* out = (float*)d_out;

    const int N = in_sizes[0] / 128;    // 50000
    const int E = in_sizes[1] / 2;      // 800000
    const int IN_FEAT = 128;
    const int F1 = 256;
    const int F2 = 64;
    const int NG = 32;
    const int T = E + N;

    // ---- workspace layout ----
    float* ws = (float*)d_ws;
    size_t o = 0;
    float* h1    = ws + o; o += (size_t)N * F1;
    float* out1  = ws + o; o += (size_t)N * F1;
    float* asrc1 = ws + o; o += (size_t)N * 4;
    float* adst1 = ws + o; o += (size_t)N * 4;
    float* asrc2 = ws + o; o += (size_t)N;
    float* adst2 = ws + o; o += (size_t)N;
    float* pools = ws + o; o += (size_t)NG * HID;
    float* cnts  = ws + o; o += (size_t)NG;
    int* ib = (int*)(ws + o);
    size_t io = 0;
    int* deg      = ib + io; io += N;
    int* rowstart = ib + io; io += N + 1;
    int* cursor   = ib + io; io += N;
    int* srcs     = ib + io; io += T;
    float* h2   = h1;                       // reuse (h1 dead after layer-1 agg)
    float* out2 = h1 + (size_t)N * F2;
    (void)ws_size; (void)n_in; (void)out_size;

    // ---- CSR build ----
    fill_i32<<<256, 256, 0, stream>>>(deg, 0, N);
    fill_i32<<<256, 256, 0, stream>>>(cursor, 0, N);
    count_k<<<(T + 255) / 256, 256, 0, stream>>>(ei, E, N, deg);
    scan_k<<<1, 1024, 0, stream>>>(deg, rowstart, N);
    scatter_k<<<(T + 255) / 256, 256, 0, stream>>>(ei, E, N, rowstart, cursor, srcs);

    // ---- layer 1 ----
    {
        dim3 g((N + 127) / 128, 2);
        sgemm_big<2><<<g, 256, 0, stream>>>(x, W1, h1, N, F1, IN_FEAT);
    }
    alpha_kernel<4><<<N, 256, 0, stream>>>(h1, a_src1, a_dst1, asrc1, adst1, N);
    gat_agg_k<4><<<N, 256, 0, stream>>>(h1, rowstart, srcs, asrc1, adst1, b1, out1, N, 1);

    // ---- layer 2 ----
    {
        dim3 g((N + 127) / 128, 1);
        sgemm_big<1><<<g, 256, 0, stream>>>(out1, W2, h2, N, F2, F1);
    }
    alpha_kernel<1><<<(N + 3) / 4, 256, 0, stream>>>(h2, a_src2, a_dst2, asrc2, adst2, N);
    gat_agg_k<1><<<N, 64, 0, stream>>>(h2, rowstart, srcs, asrc2, adst2, b2, out2, N, 0);

    // ---- pooling ----
    fill_f32<<<8, 256, 0, stream>>>(pools, 0.f, (long)NG * HID);
    fill_f32<<<1, 32, 0, stream>>>(cnts, 0.f, (long)NG);
    pool_k<<<(N + 127) / 128, 64, 0, stream>>>(out2, batch, pools, cnts, N);
    finalize_k<<<NG, HID, 0, stream>>>(pools, cnts, out);
}

// Round 4
// 486.251 us; speedup vs baseline: 3.3002x; 1.0313x over previous
//
#include <hip/hip_runtime.h>
#include <cmath>

#define HID 64
typedef unsigned short ushort_t;

__device__ inline ushort_t f2b(float f) {
    unsigned u = __float_as_uint(f);
    unsigned r = (u + 0x7fffu + ((u >> 16) & 1u)) >> 16;
    return (ushort_t)r;
}
__device__ inline float b2f(ushort_t b) { return __uint_as_float(((unsigned)b) << 16); }

// ---------------- fills ----------------

__global__ void fill_f32(float* __restrict__ p, float v, long n) {
    long i = (long)blockIdx.x * blockDim.x + threadIdx.x;
    long stride = (long)gridDim.x * blockDim.x;
    for (; i < n; i += stride) p[i] = v;
}

__global__ void fill_i32(int* __restrict__ p, int v, long n) {
    long i = (long)blockIdx.x * blockDim.x + threadIdx.x;
    long stride = (long)gridDim.x * blockDim.x;
    for (; i < n; i += stride) p[i] = v;
}

// ---------------- SGEMM: C = A[M,K] @ B[K,N], dual f32 + bf16 output ----------------
template<int NQ>
__global__ __launch_bounds__(256) void sgemm_big(const float* __restrict__ A,
                                                 const float* __restrict__ B,
                                                 float* __restrict__ C,
                                                 ushort_t* __restrict__ Cb,
                                                 int M, int N, int K) {
    const int BN = NQ * 64;
    const int bm = blockIdx.x * 128;
    const int bn = blockIdx.y * BN;
    const int tid = threadIdx.x;
    const int tx = tid & 15;
    const int ty = tid >> 4;
    __shared__ float As[16][128];
    __shared__ float Bs[16][NQ * 64];
    float acc[2][NQ][4][4] = {};

    for (int k0 = 0; k0 < K; k0 += 16) {
        #pragma unroll
        for (int it = 0; it < 2; ++it) {
            int r = (tid >> 2) + it * 64;
            int kg = (tid & 3) * 4;
            int gm = bm + r;
            float4 v = make_float4(0.f, 0.f, 0.f, 0.f);
            if (gm < M) v = *(const float4*)&A[(size_t)gm * K + k0 + kg];
            As[kg + 0][r] = v.x; As[kg + 1][r] = v.y;
            As[kg + 2][r] = v.z; As[kg + 3][r] = v.w;
        }
        #pragma unroll
        for (int it = 0; it < NQ; ++it) {
            int k = tid >> 4;
            int c = (tid & 15) * 4 + it * 64;
            float4 v = make_float4(0.f, 0.f, 0.f, 0.f);
            if (bn + c < N) v = *(const float4*)&B[(size_t)(k0 + k) * N + bn + c];
            *(float4*)&Bs[k][c] = v;
        }
        __syncthreads();
        #pragma unroll
        for (int k = 0; k < 16; ++k) {
            float a[2][4], b[NQ][4];
            #pragma unroll
            for (int q = 0; q < 2; ++q)
                *(float4*)a[q] = *(const float4*)&As[k][ty * 4 + q * 64];
            #pragma unroll
            for (int q = 0; q < NQ; ++q)
                *(float4*)b[q] = *(const float4*)&Bs[k][tx * 4 + q * 64];
            #pragma unroll
            for (int qi = 0; qi < 2; ++qi)
                #pragma unroll
                for (int qj = 0; qj < NQ; ++qj)
                    #pragma unroll
                    for (int i = 0; i < 4; ++i)
                        #pragma unroll
                        for (int j = 0; j < 4; ++j)
                            acc[qi][qj][i][j] += a[qi][i] * b[qj][j];
        }
        __syncthreads();
    }
    #pragma unroll
    for (int qi = 0; qi < 2; ++qi)
        #pragma unroll
        for (int i = 0; i < 4; ++i) {
            int gm = bm + qi * 64 + ty * 4 + i;
            if (gm >= M) continue;
            #pragma unroll
            for (int qj = 0; qj < NQ; ++qj) {
                int gn = bn + qj * 64 + tx * 4;
                if (gn < N) {
                    float4 v = make_float4(acc[qi][qj][i][0], acc[qi][qj][i][1],
                                           acc[qi][qj][i][2], acc[qi][qj][i][3]);
                    *(float4*)&C[(size_t)gm * N + gn] = v;
                    ushort4 b4;
                    b4.x = f2b(v.x); b4.y = f2b(v.y);
                    b4.z = f2b(v.z); b4.w = f2b(v.w);
                    *(ushort4*)&Cb[(size_t)gm * N + gn] = b4;
                }
            }
        }
}

// ---------------- per-node alpha dot products ----------------
template<int H>
__global__ __launch_bounds__(256) void alpha_kernel(const float* __restrict__ h,
                                                    const float* __restrict__ a_src,
                                                    const float* __restrict__ a_dst,
                                                    float* __restrict__ os,
                                                    float* __restrict__ od, int N) {
    const int F = H * HID;
    const int NPB = 256 / F;
    int t = threadIdx.x;
    int ln = t / F;
    int tt = t - ln * F;
    int n = blockIdx.x * NPB + ln;
    if (n >= N) return;
    float hv = h[(size_t)n * F + tt];
    float s = hv * a_src[tt];
    float d = hv * a_dst[tt];
    #pragma unroll
    for (int off = 32; off > 0; off >>= 1) {
        s += __shfl_down(s, off, 64);
        d += __shfl_down(d, off, 64);
    }
    if ((t & 63) == 0) {
        int head = tt >> 6;
        os[(size_t)n * H + head] = s;
        od[(size_t)n * H + head] = d;
    }
}

// ---------------- CSR build ----------------

__global__ void count_k(const int* __restrict__ ei, int E, int N, int* __restrict__ deg) {
    int e = blockIdx.x * blockDim.x + threadIdx.x;
    int T = E + N;
    if (e >= T) return;
    int d = (e < E) ? ei[E + e] : (e - E);
    atomicAdd(&deg[d], 1);
}

__global__ __launch_bounds__(1024) void scan_k(const int* __restrict__ deg,
                                               int* __restrict__ rowstart, int N) {
    __shared__ int sums[1024];
    int t = threadIdx.x;
    int chunk = (N + 1023) >> 10;
    int lo = t * chunk;
    int hi = lo + chunk; if (hi > N) hi = N;
    if (lo > N) lo = N;
    int s = 0;
    for (int i = lo; i < hi; ++i) s += deg[i];
    sums[t] = s;
    __syncthreads();
    for (int d = 1; d < 1024; d <<= 1) {
        int v = (t >= d) ? sums[t - d] : 0;
        __syncthreads();
        sums[t] += v;
        __syncthreads();
    }
    int off = sums[t] - s;
    for (int i = lo; i < hi; ++i) { rowstart[i] = off; off += deg[i]; }
    if (t == 1023) rowstart[N] = sums[1023];
}

__global__ void scatter_k(const int* __restrict__ ei, int E, int N,
                          const int* __restrict__ rowstart, int* __restrict__ cursor,
                          int* __restrict__ srcs) {
    int e = blockIdx.x * blockDim.x + threadIdx.x;
    int T = E + N;
    if (e >= T) return;
    int s, d;
    if (e < E) { s = ei[e]; d = ei[E + e]; } else { s = e - E; d = s; }
    int p = atomicAdd(&cursor[d], 1);
    srcs[rowstart[d] + p] = s;
}

// ---------------- fused per-destination GAT aggregation (bf16 gather) ----------------
#define MAXD 128
template<int H>
__global__ __launch_bounds__(H * 64) void gat_agg_k(const ushort_t* __restrict__ hb,
                                                    const int* __restrict__ rowstart,
                                                    const int* __restrict__ srcs,
                                                    const float* __restrict__ as,
                                                    const float* __restrict__ ad,
                                                    const float* __restrict__ bias,
                                                    float* __restrict__ out,
                                                    int N, int relu) {
    const int F = H * HID;
    const int SWP = (H == 1) ? 1 : (H + 1);  // pad stride coprime w/ 32 banks
    int d = blockIdx.x;
    if (d >= N) return;
    int t = threadIdx.x;
    int head = t >> 6;
    int lane = t & 63;
    int beg = rowstart[d];
    int deg = rowstart[d + 1] - beg;
    int dcap = deg < MAXD ? deg : MAXD;

    __shared__ int ssrc[MAXD];
    __shared__ float sw[MAXD * ((H == 1) ? 1 : (H + 1))];

    for (int i = t; i < dcap; i += H * 64) ssrc[i] = srcs[beg + i];
    __syncthreads();

    float adv = ad[d * H + head];

    // pass A: logits + max
    float vmax = -INFINITY;
    for (int i = lane; i < deg; i += 64) {
        int s = (i < MAXD) ? ssrc[i] : srcs[beg + i];
        float v = as[s * H + head] + adv;
        v = v > 0.f ? v : 0.2f * v;
        if (i < MAXD) sw[i * SWP + head] = v;
        vmax = fmaxf(vmax, v);
    }
    #pragma unroll
    for (int off = 32; off > 0; off >>= 1) vmax = fmaxf(vmax, __shfl_xor(vmax, off, 64));

    // pass B: exp + sum
    float dsum = 0.f;
    for (int i = lane; i < deg; i += 64) {
        float v;
        if (i < MAXD) v = sw[i * SWP + head];
        else {
            int s = srcs[beg + i];
            v = as[s * H + head] + adv;
            v = v > 0.f ? v : 0.2f * v;
        }
        float e = __expf(v - vmax);
        if (i < MAXD) sw[i * SWP + head] = e;
        dsum += e;
    }
    #pragma unroll
    for (int off = 32; off > 0; off >>= 1) dsum += __shfl_xor(dsum, off, 64);
    float rden = 1.f / (dsum + 1e-16f);

    // pass C: normalize cached weights
    for (int i = lane; i < dcap; i += 64) sw[i * SWP + head] *= rden;

    // accumulate: wave-uniform src index via readfirstlane -> SGPR-based gather
    float acc = 0.f;
    const ushort_t* __restrict__ hb_t = hb + t;
    int i = 0;
    for (; i + 4 <= dcap; i += 4) {
        int s0 = __builtin_amdgcn_readfirstlane(ssrc[i]);
        int s1 = __builtin_amdgcn_readfirstlane(ssrc[i + 1]);
        int s2 = __builtin_amdgcn_readfirstlane(ssrc[i + 2]);
        int s3 = __builtin_amdgcn_readfirstlane(ssrc[i + 3]);
        float w0 = sw[(i + 0) * SWP + head], w1 = sw[(i + 1) * SWP + head];
        float w2 = sw[(i + 2) * SWP + head], w3 = sw[(i + 3) * SWP + head];
        float g0 = b2f(hb_t[(size_t)s0 * F]);
        float g1 = b2f(hb_t[(size_t)s1 * F]);
        float g2 = b2f(hb_t[(size_t)s2 * F]);
        float g3 = b2f(hb_t[(size_t)s3 * F]);
        acc = fmaf(g0, w0, acc);
        acc = fmaf(g1, w1, acc);
        acc = fmaf(g2, w2, acc);
        acc = fmaf(g3, w3, acc);
    }
    for (; i < dcap; ++i) {
        int s = __builtin_amdgcn_readfirstlane(ssrc[i]);
        acc = fmaf(b2f(hb_t[(size_t)s * F]), sw[i * SWP + head], acc);
    }
    for (int j = MAXD; j < deg; ++j) {
        int s = srcs[beg + j];
        float v = as[s * H + head] + adv;
        v = v > 0.f ? v : 0.2f * v;
        acc = fmaf(b2f(hb_t[(size_t)s * F]), __expf(v - vmax) * rden, acc);
    }

    float o = acc + bias[t];
    if (relu) o = fmaxf(o, 0.f);
    out[(size_t)d * F + t] = o;
}

// ---------------- pooling ----------------
__global__ void pool_k(const float* __restrict__ h, const int* __restrict__ batch,
                       float* __restrict__ pool, float* __restrict__ cnt, int N) {
    const int NPB = 128;
    int c = threadIdx.x;
    int start = blockIdx.x * NPB;
    int end = min(start + NPB, N);
    float acc = 0.f;
    float cl = 0.f;
    int cur = -1;
    for (int n = start; n < end; ++n) {
        int b = batch[n];
        if (b != cur) {
            if (cur >= 0) {
                atomicAdd(&pool[cur * HID + c], acc);
                if (c == 0) atomicAdd(&cnt[cur], cl);
            }
            cur = b; acc = 0.f; cl = 0.f;
        }
        acc += h[(size_t)n * HID + c];
        cl += 1.f;
    }
    if (cur >= 0) {
        atomicAdd(&pool[cur * HID + c], acc);
        if (c == 0) atomicAdd(&cnt[cur], cl);
    }
}

__global__ void finalize_k(const float* __restrict__ pool, const float* __restrict__ cnt,
                           float* __restrict__ out) {
    int g = blockIdx.x;
    int c = threadIdx.x;
    out[g * HID + c] = pool[g * HID + c] / fmaxf(cnt[g], 1.f);
}

// ---------------- launch ----------------

extern "C" void kernel_launch(void* const* d_in, const int* in_sizes, int n_in,
                              void* d_out, int out_size, void* d_ws, size_t ws_size,
                              hipStream_t stream) {
    const float* x      = (const float*)d_in[0];
    const int*   ei     = (const int*)d_in[1];
    const int*   batch  = (const int*)d_in[2];
    const float* W1     = (const float*)d_in[3];
    const float* a_src1 = (const float*)d_in[4];
    const float* a_dst1 = (const float*)d_in[5];
    const float* b1     = (const float*)d_in[6];
    const float* W2     = (const float*)d_in[7];
    const float* a_src2 = (const float*)d_in[8];
    const float* a_dst2 = (const float*)d_in[9];
    const float* b2     = (const float*)d_in[10];
    float* out = (float*)d_out;

    const int N = in_sizes[0] / 128;    // 50000
    const int E = in_sizes[1] / 2;      // 800000
    const int IN_FEAT = 128;
    const int F1 = 256;
    const int F2 = 64;
    const int NG = 32;
    const int T = E + N;

    // ---- workspace layout ----
    float* ws = (float*)d_ws;
    size_t o = 0;
    float* h1    = ws + o; o += (size_t)N * F1;        // f32 master (alpha)
    float* out1  = ws + o; o += (size_t)N * F1;
    ushort_t* h1b = (ushort_t*)(ws + o); o += (size_t)N * F1 / 2;  // bf16 copy
    float* asrc1 = ws + o; o += (size_t)N * 4;
    float* adst1 = ws + o; o += (size_t)N * 4;
    float* asrc2 = ws + o; o += (size_t)N;
    float* adst2 = ws + o; o += (size_t)N;
    float* pools = ws + o; o += (size_t)NG * HID;
    float* cnts  = ws + o; o += (size_t)NG;
    int* ib = (int*)(ws + o);
    size_t io = 0;
    int* deg      = ib + io; io += N;
    int* rowstart = ib + io; io += N + 1;
    int* cursor   = ib + io; io += N;
    int* srcs     = ib + io; io += T;
    // layer-2 buffers overlay dead h1 region (N*256 floats):
    float* h2      = h1;                                     // N*64 f
    ushort_t* h2b  = (ushort_t*)(h1 + (size_t)N * 64);       // N*64 us = N*32 f
    float* out2    = h1 + (size_t)N * 128;                   // N*64 f
    (void)ws_size; (void)n_in; (void)out_size;

    // ---- CSR build ----
    fill_i32<<<256, 256, 0, stream>>>(deg, 0, N);
    fill_i32<<<256, 256, 0, stream>>>(cursor, 0, N);
    count_k<<<(T + 255) / 256, 256, 0, stream>>>(ei, E, N, deg);
    scan_k<<<1, 1024, 0, stream>>>(deg, rowstart, N);
    scatter_k<<<(T + 255) / 256, 256, 0, stream>>>(ei, E, N, rowstart, cursor, srcs);

    // ---- layer 1 ----
    {
        dim3 g((N + 127) / 128, 2);
        sgemm_big<2><<<g, 256, 0, stream>>>(x, W1, h1, h1b, N, F1, IN_FEAT);
    }
    alpha_kernel<4><<<N, 256, 0, stream>>>(h1, a_src1, a_dst1, asrc1, adst1, N);
    gat_agg_k<4><<<N, 256, 0, stream>>>(h1b, rowstart, srcs, asrc1, adst1, b1, out1, N, 1);

    // ---- layer 2 ----
    {
        dim3 g((N + 127) / 128, 1);
        sgemm_big<1><<<g, 256, 0, stream>>>(out1, W2, h2, h2b, N, F2, F1);
    }
    alpha_kernel<1><<<(N + 3) / 4, 256, 0, stream>>>(h2, a_src2, a_dst2, asrc2, adst2, N);
    gat_agg_k<1><<<N, 64, 0, stream>>>(h2b, rowstart, srcs, asrc2, adst2, b2, out2, N, 0);

    // ---- pooling ----
    fill_f32<<<8, 256, 0, stream>>>(pools, 0.f, (long)NG * HID);
    fill_f32<<<1, 32, 0, stream>>>(cnts, 0.f, (long)NG);
    pool_k<<<(N + 127) / 128, 64, 0, stream>>>(out2, batch, pools, cnts, N);
    finalize_k<<<NG, HID, 0, stream>>>(pools, cnts, out);
}

// Round 5
// 428.544 us; speedup vs baseline: 3.7446x; 1.1347x over previous
//
#include <hip/hip_runtime.h>
#include <cmath>

#define HID 64
typedef unsigned short ushort_t;
typedef __attribute__((ext_vector_type(8))) short bf16x8;
typedef __attribute__((ext_vector_type(4))) float f32x4;

__device__ inline ushort_t f2b(float f) {
    unsigned u = __float_as_uint(f);
    unsigned r = (u + 0x7fffu + ((u >> 16) & 1u)) >> 16;
    return (ushort_t)r;
}
__device__ inline float b2f(ushort_t b) { return __uint_as_float(((unsigned)b) << 16); }

// ---------------- fills ----------------

__global__ void fill_f32(float* __restrict__ p, float v, long n) {
    long i = (long)blockIdx.x * blockDim.x + threadIdx.x;
    long stride = (long)gridDim.x * blockDim.x;
    for (; i < n; i += stride) p[i] = v;
}

__global__ void fill_i32(int* __restrict__ p, int v, long n) {
    long i = (long)blockIdx.x * blockDim.x + threadIdx.x;
    long stride = (long)gridDim.x * blockDim.x;
    for (; i < n; i += stride) p[i] = v;
}

// ---------------- weight transpose + bf16 convert: src[K][N] f32 -> dst[N][K] bf16 ----
__global__ void transp_k(const float* __restrict__ src, ushort_t* __restrict__ dst,
                         int K, int N) {
    int k = blockIdx.x;
    int n = threadIdx.x;
    dst[(size_t)n * K + k] = f2b(src[(size_t)k * N + n]);
}

// ---------------- MFMA GEMM: C[M,BN] = A[M,K] @ Bt[BN,K]^T, output bf16 ----------------
// WM x WN waves of 64 threads; each wave computes a 64x64 tile. BK=32 chunks.
template<int WM, int WN, int K, bool AF32, bool B_WHOLE>
__global__ __launch_bounds__(256) void gemm_mfma(const void* __restrict__ Ap,
                                                 const ushort_t* __restrict__ Bt,
                                                 ushort_t* __restrict__ Cb,
                                                 int M) {
    constexpr int T = WM * WN * 64;
    constexpr int BM = WM * 64;
    constexpr int BN = WN * 64;
    constexpr int BSTR = B_WHOLE ? (K + 8) : 40;

    __shared__ ushort_t Alds[BM][40];
    __shared__ ushort_t Blds[BN][BSTR];

    const int tid = threadIdx.x;
    const int bm = blockIdx.x * BM;
    const int w = tid >> 6;
    const int l = tid & 63;
    const int lr = l >> 4;   // 0..3 (k-subblock / d-row group)
    const int lc = l & 15;
    const int row0 = (WM == 1) ? 0 : w * 64;
    const int col0 = (WN == 1) ? 0 : w * 64;

    f32x4 acc[4][4] = {};

    if (B_WHOLE) {
        constexpr int UPR = K / 8;
        for (int u = tid; u < BN * UPR; u += T) {
            int row = u / UPR, j = u % UPR;
            *(bf16x8*)&Blds[row][j * 8] = *(const bf16x8*)&Bt[(size_t)row * K + j * 8];
        }
    }

    for (int kk = 0; kk < K / 32; ++kk) {
        __syncthreads();
        // stage A chunk BM x 32
        for (int u = tid; u < BM * 4; u += T) {
            int row = u >> 2, part = u & 3;
            int gm = bm + row;
            bf16x8 v = {0, 0, 0, 0, 0, 0, 0, 0};
            if (gm < M) {
                if (AF32) {
                    const float* ap = (const float*)Ap + (size_t)gm * K + kk * 32 + part * 8;
                    float4 v0 = *(const float4*)ap;
                    float4 v1 = *(const float4*)(ap + 4);
                    v[0] = (short)f2b(v0.x); v[1] = (short)f2b(v0.y);
                    v[2] = (short)f2b(v0.z); v[3] = (short)f2b(v0.w);
                    v[4] = (short)f2b(v1.x); v[5] = (short)f2b(v1.y);
                    v[6] = (short)f2b(v1.z); v[7] = (short)f2b(v1.w);
                } else {
                    v = *(const bf16x8*)((const ushort_t*)Ap + (size_t)gm * K + kk * 32 + part * 8);
                }
            }
            *(bf16x8*)&Alds[row][part * 8] = v;
        }
        if (!B_WHOLE) {
            for (int u = tid; u < BN * 4; u += T) {
                int col = u >> 2, part = u & 3;
                *(bf16x8*)&Blds[col][part * 8] =
                    *(const bf16x8*)&Bt[(size_t)col * K + kk * 32 + part * 8];
            }
        }
        __syncthreads();

        const int koff = B_WHOLE ? kk * 32 : 0;
        bf16x8 af[4], bfr[4];
        #pragma unroll
        for (int fr = 0; fr < 4; ++fr)
            af[fr] = *(const bf16x8*)&Alds[row0 + fr * 16 + lc][lr * 8];
        #pragma unroll
        for (int fc = 0; fc < 4; ++fc)
            bfr[fc] = *(const bf16x8*)&Blds[col0 + fc * 16 + lc][koff + lr * 8];
        #pragma unroll
        for (int fr = 0; fr < 4; ++fr)
            #pragma unroll
            for (int fc = 0; fc < 4; ++fc)
                acc[fr][fc] = __builtin_amdgcn_mfma_f32_16x16x32_bf16(
                    af[fr], bfr[fc], acc[fr][fc], 0, 0, 0);
    }

    #pragma unroll
    for (int fr = 0; fr < 4; ++fr)
        #pragma unroll
        for (int r = 0; r < 4; ++r) {
            int gm = bm + row0 + fr * 16 + lr * 4 + r;
            if (gm >= M) continue;
            #pragma unroll
            for (int fc = 0; fc < 4; ++fc)
                Cb[(size_t)gm * BN + col0 + fc * 16 + lc] = f2b(acc[fr][fc][r]);
        }
}

// ---------------- per-node alpha dot products (bf16 input) ----------------
template<int H>
__global__ __launch_bounds__(256) void alpha_kernel(const ushort_t* __restrict__ h,
                                                    const float* __restrict__ a_src,
                                                    const float* __restrict__ a_dst,
                                                    float* __restrict__ os,
                                                    float* __restrict__ od, int N) {
    const int F = H * HID;
    const int NPB = 256 / F;
    int t = threadIdx.x;
    int ln = t / F;
    int tt = t - ln * F;
    int n = blockIdx.x * NPB + ln;
    if (n >= N) return;
    float hv = b2f(h[(size_t)n * F + tt]);
    float s = hv * a_src[tt];
    float d = hv * a_dst[tt];
    #pragma unroll
    for (int off = 32; off > 0; off >>= 1) {
        s += __shfl_down(s, off, 64);
        d += __shfl_down(d, off, 64);
    }
    if ((t & 63) == 0) {
        int head = tt >> 6;
        os[(size_t)n * H + head] = s;
        od[(size_t)n * H + head] = d;
    }
}

// ---------------- CSR build ----------------

__global__ void count_k(const int* __restrict__ ei, int E, int N, int* __restrict__ deg) {
    int e = blockIdx.x * blockDim.x + threadIdx.x;
    int T = E + N;
    if (e >= T) return;
    int d = (e < E) ? ei[E + e] : (e - E);
    atomicAdd(&deg[d], 1);
}

__global__ __launch_bounds__(1024) void scan_k(const int* __restrict__ deg,
                                               int* __restrict__ rowstart, int N) {
    __shared__ int sums[1024];
    int t = threadIdx.x;
    int chunk = (N + 1023) >> 10;
    int lo = t * chunk;
    int hi = lo + chunk; if (hi > N) hi = N;
    if (lo > N) lo = N;
    int s = 0;
    for (int i = lo; i < hi; ++i) s += deg[i];
    sums[t] = s;
    __syncthreads();
    for (int d = 1; d < 1024; d <<= 1) {
        int v = (t >= d) ? sums[t - d] : 0;
        __syncthreads();
        sums[t] += v;
        __syncthreads();
    }
    int off = sums[t] - s;
    for (int i = lo; i < hi; ++i) { rowstart[i] = off; off += deg[i]; }
    if (t == 1023) rowstart[N] = sums[1023];
}

__global__ void scatter_k(const int* __restrict__ ei, int E, int N,
                          const int* __restrict__ rowstart, int* __restrict__ cursor,
                          int* __restrict__ srcs) {
    int e = blockIdx.x * blockDim.x + threadIdx.x;
    int T = E + N;
    if (e >= T) return;
    int s, d;
    if (e < E) { s = ei[e]; d = ei[E + e]; } else { s = e - E; d = s; }
    int p = atomicAdd(&cursor[d], 1);
    srcs[rowstart[d] + p] = s;
}

// ---------------- fused per-destination GAT aggregation (bf16 gather) ----------------
#define MAXD 128
template<int H, bool OUTB>
__global__ __launch_bounds__(H * 64) void gat_agg_k(const ushort_t* __restrict__ hb,
                                                    const int* __restrict__ rowstart,
                                                    const int* __restrict__ srcs,
                                                    const float* __restrict__ as,
                                                    const float* __restrict__ ad,
                                                    const float* __restrict__ bias,
                                                    void* __restrict__ outv,
                                                    int N, int relu) {
    const int F = H * HID;
    const int SWP = (H == 1) ? 1 : (H + 1);
    int d = blockIdx.x;
    if (d >= N) return;
    int t = threadIdx.x;
    int head = t >> 6;
    int lane = t & 63;
    int beg = rowstart[d];
    int deg = rowstart[d + 1] - beg;
    int dcap = deg < MAXD ? deg : MAXD;

    __shared__ int ssrc[MAXD];
    __shared__ float sw[MAXD * ((H == 1) ? 1 : (H + 1))];

    for (int i = t; i < dcap; i += H * 64) ssrc[i] = srcs[beg + i];
    __syncthreads();

    float adv = ad[d * H + head];

    float vmax = -INFINITY;
    for (int i = lane; i < deg; i += 64) {
        int s = (i < MAXD) ? ssrc[i] : srcs[beg + i];
        float v = as[s * H + head] + adv;
        v = v > 0.f ? v : 0.2f * v;
        if (i < MAXD) sw[i * SWP + head] = v;
        vmax = fmaxf(vmax, v);
    }
    #pragma unroll
    for (int off = 32; off > 0; off >>= 1) vmax = fmaxf(vmax, __shfl_xor(vmax, off, 64));

    float dsum = 0.f;
    for (int i = lane; i < deg; i += 64) {
        float v;
        if (i < MAXD) v = sw[i * SWP + head];
        else {
            int s = srcs[beg + i];
            v = as[s * H + head] + adv;
            v = v > 0.f ? v : 0.2f * v;
        }
        float e = __expf(v - vmax);
        if (i < MAXD) sw[i * SWP + head] = e;
        dsum += e;
    }
    #pragma unroll
    for (int off = 32; off > 0; off >>= 1) dsum += __shfl_xor(dsum, off, 64);
    float rden = 1.f / (dsum + 1e-16f);

    for (int i = lane; i < dcap; i += 64) sw[i * SWP + head] *= rden;

    float acc = 0.f;
    const ushort_t* __restrict__ hb_t = hb + t;
    int i = 0;
    for (; i + 4 <= dcap; i += 4) {
        int s0 = __builtin_amdgcn_readfirstlane(ssrc[i]);
        int s1 = __builtin_amdgcn_readfirstlane(ssrc[i + 1]);
        int s2 = __builtin_amdgcn_readfirstlane(ssrc[i + 2]);
        int s3 = __builtin_amdgcn_readfirstlane(ssrc[i + 3]);
        float w0 = sw[(i + 0) * SWP + head], w1 = sw[(i + 1) * SWP + head];
        float w2 = sw[(i + 2) * SWP + head], w3 = sw[(i + 3) * SWP + head];
        float g0 = b2f(hb_t[(size_t)s0 * F]);
        float g1 = b2f(hb_t[(size_t)s1 * F]);
        float g2 = b2f(hb_t[(size_t)s2 * F]);
        float g3 = b2f(hb_t[(size_t)s3 * F]);
        acc = fmaf(g0, w0, acc);
        acc = fmaf(g1, w1, acc);
        acc = fmaf(g2, w2, acc);
        acc = fmaf(g3, w3, acc);
    }
    for (; i < dcap; ++i) {
        int s = __builtin_amdgcn_readfirstlane(ssrc[i]);
        acc = fmaf(b2f(hb_t[(size_t)s * F]), sw[i * SWP + head], acc);
    }
    for (int j = MAXD; j < deg; ++j) {
        int s = srcs[beg + j];
        float v = as[s * H + head] + adv;
        v = v > 0.f ? v : 0.2f * v;
        acc = fmaf(b2f(hb_t[(size_t)s * F]), __expf(v - vmax) * rden, acc);
    }

    float o = acc + bias[t];
    if (relu) o = fmaxf(o, 0.f);
    if (OUTB) ((ushort_t*)outv)[(size_t)d * F + t] = f2b(o);
    else      ((float*)outv)[(size_t)d * F + t] = o;
}

// ---------------- pooling ----------------
__global__ void pool_k(const float* __restrict__ h, const int* __restrict__ batch,
                       float* __restrict__ pool, float* __restrict__ cnt, int N) {
    const int NPB = 128;
    int c = threadIdx.x;
    int start = blockIdx.x * NPB;
    int end = min(start + NPB, N);
    float acc = 0.f;
    float cl = 0.f;
    int cur = -1;
    for (int n = start; n < end; ++n) {
        int b = batch[n];
        if (b != cur) {
            if (cur >= 0) {
                atomicAdd(&pool[cur * HID + c], acc);
                if (c == 0) atomicAdd(&cnt[cur], cl);
            }
            cur = b; acc = 0.f; cl = 0.f;
        }
        acc += h[(size_t)n * HID + c];
        cl += 1.f;
    }
    if (cur >= 0) {
        atomicAdd(&pool[cur * HID + c], acc);
        if (c == 0) atomicAdd(&cnt[cur], cl);
    }
}

__global__ void finalize_k(const float* __restrict__ pool, const float* __restrict__ cnt,
                           float* __restrict__ out) {
    int g = blockIdx.x;
    int c = threadIdx.x;
    out[g * HID + c] = pool[g * HID + c] / fmaxf(cnt[g], 1.f);
}

// ---------------- launch ----------------

extern "C" void kernel_launch(void* const* d_in, const int* in_sizes, int n_in,
                              void* d_out, int out_size, void* d_ws, size_t ws_size,
                              hipStream_t stream) {
    const float* x      = (const float*)d_in[0];
    const int*   ei     = (const int*)d_in[1];
    const int*   batch  = (const int*)d_in[2];
    const float* W1     = (const float*)d_in[3];
    const float* a_src1 = (const float*)d_in[4];
    const float* a_dst1 = (const float*)d_in[5];
    const float* b1     = (const float*)d_in[6];
    const float* W2     = (const float*)d_in[7];
    const float* a_src2 = (const float*)d_in[8];
    const float* a_dst2 = (const float*)d_in[9];
    const float* b2     = (const float*)d_in[10];
    float* out = (float*)d_out;

    const int N = in_sizes[0] / 128;    // 50000
    const int E = in_sizes[1] / 2;      // 800000
    const int F1 = 256;
    const int F2 = 64;
    const int NG = 32;
    const int T = E + N;

    // ---- workspace layout (float units) ----
    float* ws = (float*)d_ws;
    size_t o = 0;
    ushort_t* h1b   = (ushort_t*)(ws + o); o += (size_t)N * F1 / 2;  // [N][256] bf16
    ushort_t* out1b = (ushort_t*)(ws + o); o += (size_t)N * F1 / 2;
    ushort_t* h2b   = (ushort_t*)(ws + o); o += (size_t)N * F2 / 2;
    float* out2  = ws + o; o += (size_t)N * F2;
    float* asrc1 = ws + o; o += (size_t)N * 4;
    float* adst1 = ws + o; o += (size_t)N * 4;
    float* asrc2 = ws + o; o += (size_t)N;
    float* adst2 = ws + o; o += (size_t)N;
    float* pools = ws + o; o += (size_t)NG * HID;
    float* cnts  = ws + o; o += (size_t)NG;
    ushort_t* W1t = (ushort_t*)(ws + o); o += 256 * 128 / 2;   // [256][128] bf16
    ushort_t* W2t = (ushort_t*)(ws + o); o += 64 * 256 / 2;    // [64][256] bf16
    int* ib = (int*)(ws + o);
    size_t io = 0;
    int* deg      = ib + io; io += N;
    int* rowstart = ib + io; io += N + 1;
    int* cursor   = ib + io; io += N;
    int* srcs     = ib + io; io += T;
    (void)ws_size; (void)n_in; (void)out_size;

    // ---- weight transposes (f32 -> bf16 [N][K]) ----
    transp_k<<<128, 256, 0, stream>>>(W1, W1t, 128, 256);
    transp_k<<<256, 64, 0, stream>>>(W2, W2t, 256, 64);

    // ---- CSR build ----
    fill_i32<<<256, 256, 0, stream>>>(deg, 0, N);
    fill_i32<<<256, 256, 0, stream>>>(cursor, 0, N);
    count_k<<<(T + 255) / 256, 256, 0, stream>>>(ei, E, N, deg);
    scan_k<<<1, 1024, 0, stream>>>(deg, rowstart, N);
    scatter_k<<<(T + 255) / 256, 256, 0, stream>>>(ei, E, N, rowstart, cursor, srcs);

    // ---- layer 1: h1 = x @ W1 (f32 A fused-converted, bf16 MFMA) ----
    gemm_mfma<1, 4, 128, true, false><<<(N + 63) / 64, 256, 0, stream>>>(x, W1t, h1b, N);
    alpha_kernel<4><<<N, 256, 0, stream>>>(h1b, a_src1, a_dst1, asrc1, adst1, N);
    gat_agg_k<4, true><<<N, 256, 0, stream>>>(h1b, rowstart, srcs, asrc1, adst1, b1, out1b, N, 1);

    // ---- layer 2: h2 = out1 @ W2 ----
    gemm_mfma<2, 1, 256, false, true><<<(N + 127) / 128, 128, 0, stream>>>(out1b, W2t, h2b, N);
    alpha_kernel<1><<<(N + 3) / 4, 256, 0, stream>>>(h2b, a_src2, a_dst2, asrc2, adst2, N);
    gat_agg_k<1, false><<<N, 64, 0, stream>>>(h2b, rowstart, srcs, asrc2, adst2, b2, out2, N, 0);

    // ---- pooling ----
    fill_f32<<<8, 256, 0, stream>>>(pools, 0.f, (long)NG * HID);
    fill_f32<<<1, 32, 0, stream>>>(cnts, 0.f, (long)NG);
    pool_k<<<(N + 127) / 128, 64, 0, stream>>>(out2, batch, pools, cnts, N);
    finalize_k<<<NG, HID, 0, stream>>>(pools, cnts, out);
}

// Round 6
// 360.620 us; speedup vs baseline: 4.4499x; 1.1884x over previous
//
#include <hip/hip_runtime.h>
#include <cmath>

#define HID 64
typedef unsigned short ushort_t;
typedef __attribute__((ext_vector_type(8))) short bf16x8;
typedef __attribute__((ext_vector_type(4))) float f32x4;

__device__ inline ushort_t f2b(float f) {
    unsigned u = __float_as_uint(f);
    unsigned r = (u + 0x7fffu + ((u >> 16) & 1u)) >> 16;
    return (ushort_t)r;
}
__device__ inline float b2f(ushort_t b) { return __uint_as_float(((unsigned)b) << 16); }

// ---------------- fills ----------------

__global__ void fill_f32(float* __restrict__ p, float v, long n) {
    long i = (long)blockIdx.x * blockDim.x + threadIdx.x;
    long stride = (long)gridDim.x * blockDim.x;
    for (; i < n; i += stride) p[i] = v;
}

__global__ void fill_i32(int* __restrict__ p, int v, long n) {
    long i = (long)blockIdx.x * blockDim.x + threadIdx.x;
    long stride = (long)gridDim.x * blockDim.x;
    for (; i < n; i += stride) p[i] = v;
}

// ---------------- weight transpose + bf16 convert: src[K][N] f32 -> dst[N][K] bf16 ----
__global__ void transp_k(const float* __restrict__ src, ushort_t* __restrict__ dst,
                         int K, int N) {
    int k = blockIdx.x;
    int n = threadIdx.x;
    dst[(size_t)n * K + k] = f2b(src[(size_t)k * N + n]);
}

// ---------------- MFMA GEMM with fused alpha epilogue ----------------
// C[M,BN] = A[M,K] @ Bt[BN,K]^T (bf16 out). If AH>0 also writes
// alpha_src/alpha_dst[M][AH] from the f32 accumulators.
template<int WM, int WN, int K, bool AF32, bool B_WHOLE, int AH>
__global__ __launch_bounds__(WM * WN * 64) void gemm_mfma(
        const void* __restrict__ Ap, const ushort_t* __restrict__ Bt,
        ushort_t* __restrict__ Cb, const float* __restrict__ a_src,
        const float* __restrict__ a_dst, float* __restrict__ os,
        float* __restrict__ od, int M) {
    constexpr int T = WM * WN * 64;
    constexpr int BM = WM * 64;
    constexpr int BN = WN * 64;
    constexpr int BSTR = B_WHOLE ? (K + 8) : 40;

    __shared__ ushort_t Alds[BM][40];
    __shared__ ushort_t Blds[BN][BSTR];

    const int tid = threadIdx.x;
    const int bm = blockIdx.x * BM;
    const int w = tid >> 6;
    const int l = tid & 63;
    const int lr = l >> 4;
    const int lc = l & 15;
    const int row0 = (WM == 1) ? 0 : w * 64;
    const int col0 = (WN == 1) ? 0 : w * 64;

    f32x4 acc[4][4] = {};

    if (B_WHOLE) {
        constexpr int UPR = K / 8;
        for (int u = tid; u < BN * UPR; u += T) {
            int row = u / UPR, j = u % UPR;
            *(bf16x8*)&Blds[row][j * 8] = *(const bf16x8*)&Bt[(size_t)row * K + j * 8];
        }
    }

    for (int kk = 0; kk < K / 32; ++kk) {
        __syncthreads();
        for (int u = tid; u < BM * 4; u += T) {
            int row = u >> 2, part = u & 3;
            int gm = bm + row;
            bf16x8 v = {0, 0, 0, 0, 0, 0, 0, 0};
            if (gm < M) {
                if (AF32) {
                    const float* ap = (const float*)Ap + (size_t)gm * K + kk * 32 + part * 8;
                    float4 v0 = *(const float4*)ap;
                    float4 v1 = *(const float4*)(ap + 4);
                    v[0] = (short)f2b(v0.x); v[1] = (short)f2b(v0.y);
                    v[2] = (short)f2b(v0.z); v[3] = (short)f2b(v0.w);
                    v[4] = (short)f2b(v1.x); v[5] = (short)f2b(v1.y);
                    v[6] = (short)f2b(v1.z); v[7] = (short)f2b(v1.w);
                } else {
                    v = *(const bf16x8*)((const ushort_t*)Ap + (size_t)gm * K + kk * 32 + part * 8);
                }
            }
            *(bf16x8*)&Alds[row][part * 8] = v;
        }
        if (!B_WHOLE) {
            for (int u = tid; u < BN * 4; u += T) {
                int col = u >> 2, part = u & 3;
                *(bf16x8*)&Blds[col][part * 8] =
                    *(const bf16x8*)&Bt[(size_t)col * K + kk * 32 + part * 8];
            }
        }
        __syncthreads();

        const int koff = B_WHOLE ? kk * 32 : 0;
        bf16x8 af[4], bfr[4];
        #pragma unroll
        for (int fr = 0; fr < 4; ++fr)
            af[fr] = *(const bf16x8*)&Alds[row0 + fr * 16 + lc][lr * 8];
        #pragma unroll
        for (int fc = 0; fc < 4; ++fc)
            bfr[fc] = *(const bf16x8*)&Blds[col0 + fc * 16 + lc][koff + lr * 8];
        #pragma unroll
        for (int fr = 0; fr < 4; ++fr)
            #pragma unroll
            for (int fc = 0; fc < 4; ++fc)
                acc[fr][fc] = __builtin_amdgcn_mfma_f32_16x16x32_bf16(
                    af[fr], bfr[fc], acc[fr][fc], 0, 0, 0);
    }

    #pragma unroll
    for (int fr = 0; fr < 4; ++fr)
        #pragma unroll
        for (int r = 0; r < 4; ++r) {
            int gm = bm + row0 + fr * 16 + lr * 4 + r;
            if (gm >= M) continue;
            #pragma unroll
            for (int fc = 0; fc < 4; ++fc)
                Cb[(size_t)gm * BN + col0 + fc * 16 + lc] = f2b(acc[fr][fc][r]);
        }

    if (AH > 0) {
        const int head = (WN > 1) ? w : 0;
        const float* __restrict__ asv = a_src + head * 64;
        const float* __restrict__ adv = a_dst + head * 64;
        #pragma unroll
        for (int fr = 0; fr < 4; ++fr)
            #pragma unroll
            for (int r = 0; r < 4; ++r) {
                float ps = 0.f, pd = 0.f;
                #pragma unroll
                for (int fc = 0; fc < 4; ++fc) {
                    float av = acc[fr][fc][r];
                    ps = fmaf(av, asv[fc * 16 + lc], ps);
                    pd = fmaf(av, adv[fc * 16 + lc], pd);
                }
                #pragma unroll
                for (int off = 1; off < 16; off <<= 1) {
                    ps += __shfl_xor(ps, off, 64);
                    pd += __shfl_xor(pd, off, 64);
                }
                int gm = bm + row0 + fr * 16 + lr * 4 + r;
                if (lc == 0 && gm < M) {
                    os[(size_t)gm * AH + head] = ps;
                    od[(size_t)gm * AH + head] = pd;
                }
            }
    }
}

// ---------------- CSR build ----------------

__global__ void count_k(const int* __restrict__ ei, int E, int N, int* __restrict__ deg) {
    int e = blockIdx.x * blockDim.x + threadIdx.x;
    int T = E + N;
    if (e >= T) return;
    int d = (e < E) ? ei[E + e] : (e - E);
    atomicAdd(&deg[d], 1);
}

__global__ __launch_bounds__(1024) void scan_k(const int* __restrict__ deg,
                                               int* __restrict__ rowstart, int N) {
    __shared__ int sums[1024];
    int t = threadIdx.x;
    int chunk = (N + 1023) >> 10;
    int lo = t * chunk;
    int hi = lo + chunk; if (hi > N) hi = N;
    if (lo > N) lo = N;
    int s = 0;
    for (int i = lo; i < hi; ++i) s += deg[i];
    sums[t] = s;
    __syncthreads();
    for (int d = 1; d < 1024; d <<= 1) {
        int v = (t >= d) ? sums[t - d] : 0;
        __syncthreads();
        sums[t] += v;
        __syncthreads();
    }
    int off = sums[t] - s;
    for (int i = lo; i < hi; ++i) { rowstart[i] = off; off += deg[i]; }
    if (t == 1023) rowstart[N] = sums[1023];
}

__global__ void scatter_k(const int* __restrict__ ei, int E, int N,
                          const int* __restrict__ rowstart, int* __restrict__ cursor,
                          int* __restrict__ srcs) {
    int e = blockIdx.x * blockDim.x + threadIdx.x;
    int T = E + N;
    if (e >= T) return;
    int s, d;
    if (e < E) { s = ei[e]; d = ei[E + e]; } else { s = e - E; d = s; }
    int p = atomicAdd(&cursor[d], 1);
    srcs[rowstart[d] + p] = s;
}

// ---------------- GAT aggregation, H=4: one wave per destination ----------------
#define MAXD 128
__global__ __launch_bounds__(256) void gat_agg4(const ushort_t* __restrict__ hb,
        const int* __restrict__ rowstart, const int* __restrict__ srcs,
        const float* __restrict__ as, const float* __restrict__ ad,
        const float* __restrict__ bias, ushort_t* __restrict__ outb, int N) {
    __shared__ int ssrc_s[4][MAXD];
    __shared__ float sw_s[4][MAXD][4];
    __shared__ float hstat_s[4][2][4];
    const int wave = threadIdx.x >> 6;
    const int lane = threadIdx.x & 63;
    int d = blockIdx.x * 4 + wave;
    if (d >= N) return;
    int* ssrc = ssrc_s[wave];
    float (*sw)[4] = sw_s[wave];
    int beg = rowstart[d];
    int deg = rowstart[d + 1] - beg;
    int dcap = deg < MAXD ? deg : MAXD;
    for (int i = lane; i < dcap; i += 64) ssrc[i] = srcs[beg + i];

    // phase 1: softmax weights; lane = (edge_slot<<2) | head
    const int isub = lane >> 2;
    const int hd = lane & 3;
    float adv = ad[d * 4 + hd];
    float vmax = -INFINITY;
    for (int e0 = 0; e0 < deg; e0 += 16) {
        int e = e0 + isub;
        if (e < deg) {
            int s = (e < MAXD) ? ssrc[e] : srcs[beg + e];
            float v = as[s * 4 + hd] + adv;
            v = v > 0.f ? v : 0.2f * v;
            if (e < MAXD) sw[e][hd] = v;
            vmax = fmaxf(vmax, v);
        }
    }
    #pragma unroll
    for (int off = 4; off < 64; off <<= 1) vmax = fmaxf(vmax, __shfl_xor(vmax, off, 64));
    float dsum = 0.f;
    for (int e0 = 0; e0 < deg; e0 += 16) {
        int e = e0 + isub;
        if (e < deg) {
            float v;
            if (e < MAXD) v = sw[e][hd];
            else {
                int s = srcs[beg + e];
                v = as[s * 4 + hd] + adv;
                v = v > 0.f ? v : 0.2f * v;
            }
            float ex = __expf(v - vmax);
            if (e < MAXD) sw[e][hd] = ex;
            dsum += ex;
        }
    }
    #pragma unroll
    for (int off = 4; off < 64; off <<= 1) dsum += __shfl_xor(dsum, off, 64);
    float rden = 1.f / (dsum + 1e-16f);
    for (int e0 = 0; e0 < dcap; e0 += 16) {
        int e = e0 + isub;
        if (e < dcap) sw[e][hd] *= rden;
    }
    if (deg > MAXD && isub == 0) {
        hstat_s[wave][0][hd] = vmax;
        hstat_s[wave][1][hd] = rden;
    }

    // phase 2: lane covers channels [lane*4, lane*4+4)
    const int hd2 = lane >> 4;
    const ushort_t* __restrict__ hrow = hb + (size_t)(lane * 4);
    float a0 = 0.f, a1 = 0.f, a2 = 0.f, a3 = 0.f;
    int e = 0;
    for (; e + 2 <= dcap; e += 2) {
        int s0 = __builtin_amdgcn_readfirstlane(ssrc[e]);
        int s1 = __builtin_amdgcn_readfirstlane(ssrc[e + 1]);
        float w0 = sw[e][hd2], w1 = sw[e + 1][hd2];
        ushort4 g0 = *(const ushort4*)(hrow + (size_t)s0 * 256);
        ushort4 g1 = *(const ushort4*)(hrow + (size_t)s1 * 256);
        a0 = fmaf(b2f(g0.x), w0, a0); a1 = fmaf(b2f(g0.y), w0, a1);
        a2 = fmaf(b2f(g0.z), w0, a2); a3 = fmaf(b2f(g0.w), w0, a3);
        a0 = fmaf(b2f(g1.x), w1, a0); a1 = fmaf(b2f(g1.y), w1, a1);
        a2 = fmaf(b2f(g1.z), w1, a2); a3 = fmaf(b2f(g1.w), w1, a3);
    }
    for (; e < dcap; ++e) {
        int s = __builtin_amdgcn_readfirstlane(ssrc[e]);
        float w = sw[e][hd2];
        ushort4 g = *(const ushort4*)(hrow + (size_t)s * 256);
        a0 = fmaf(b2f(g.x), w, a0); a1 = fmaf(b2f(g.y), w, a1);
        a2 = fmaf(b2f(g.z), w, a2); a3 = fmaf(b2f(g.w), w, a3);
    }
    if (deg > MAXD) {
        float vm2 = hstat_s[wave][0][hd2];
        float rd2 = hstat_s[wave][1][hd2];
        float adv2 = ad[d * 4 + hd2];
        for (int j = MAXD; j < deg; ++j) {
            int s = srcs[beg + j];
            float v = as[s * 4 + hd2] + adv2;
            v = v > 0.f ? v : 0.2f * v;
            float w = __expf(v - vm2) * rd2;
            ushort4 g = *(const ushort4*)(hrow + (size_t)s * 256);
            a0 = fmaf(b2f(g.x), w, a0); a1 = fmaf(b2f(g.y), w, a1);
            a2 = fmaf(b2f(g.z), w, a2); a3 = fmaf(b2f(g.w), w, a3);
        }
    }
    int cb = lane * 4;
    ushort4 ov;
    ov.x = f2b(fmaxf(a0 + bias[cb + 0], 0.f));
    ov.y = f2b(fmaxf(a1 + bias[cb + 1], 0.f));
    ov.z = f2b(fmaxf(a2 + bias[cb + 2], 0.f));
    ov.w = f2b(fmaxf(a3 + bias[cb + 3], 0.f));
    *(ushort4*)&outb[(size_t)d * 256 + cb] = ov;
}

// ---------------- GAT aggregation, H=1: one wave per destination, 4 edges/iter ----
__global__ __launch_bounds__(256) void gat_agg1(const ushort_t* __restrict__ hb,
        const int* __restrict__ rowstart, const int* __restrict__ srcs,
        const float* __restrict__ as, const float* __restrict__ ad,
        const float* __restrict__ bias, float* __restrict__ out2, int N) {
    __shared__ int ssrc_s[4][MAXD];
    __shared__ float sw_s[4][MAXD];
    const int wave = threadIdx.x >> 6;
    const int lane = threadIdx.x & 63;
    int d = blockIdx.x * 4 + wave;
    if (d >= N) return;
    int* ssrc = ssrc_s[wave];
    float* sw = sw_s[wave];
    int beg = rowstart[d];
    int deg = rowstart[d + 1] - beg;
    int dcap = deg < MAXD ? deg : MAXD;
    for (int i = lane; i < dcap; i += 64) ssrc[i] = srcs[beg + i];

    float adv = ad[d];
    float vmax = -INFINITY;
    for (int e0 = 0; e0 < deg; e0 += 64) {
        int e = e0 + lane;
        if (e < deg) {
            int s = (e < MAXD) ? ssrc[e] : srcs[beg + e];
            float v = as[s] + adv;
            v = v > 0.f ? v : 0.2f * v;
            if (e < MAXD) sw[e] = v;
            vmax = fmaxf(vmax, v);
        }
    }
    #pragma unroll
    for (int off = 1; off < 64; off <<= 1) vmax = fmaxf(vmax, __shfl_xor(vmax, off, 64));
    float dsum = 0.f;
    for (int e0 = 0; e0 < deg; e0 += 64) {
        int e = e0 + lane;
        if (e < deg) {
            float v;
            if (e < MAXD) v = sw[e];
            else {
                int s = srcs[beg + e];
                v = as[s] + adv;
                v = v > 0.f ? v : 0.2f * v;
            }
            float ex = __expf(v - vmax);
            if (e < MAXD) sw[e] = ex;
            dsum += ex;
        }
    }
    #pragma unroll
    for (int off = 1; off < 64; off <<= 1) dsum += __shfl_xor(dsum, off, 64);
    float rden = 1.f / (dsum + 1e-16f);
    for (int e0 = 0; e0 < dcap; e0 += 64) {
        int e = e0 + lane;
        if (e < dcap) sw[e] *= rden;
    }

    // phase 2: lane = (edge_slot<<4) | channel_group; 4 edges per iteration
    const int esub = lane >> 4;
    const int cg = lane & 15;
    const ushort_t* __restrict__ hrow = hb + (size_t)(cg * 4);
    float a0 = 0.f, a1 = 0.f, a2 = 0.f, a3 = 0.f;
    int e0 = 0;
    for (; e0 + 4 <= dcap; e0 += 4) {
        int e = e0 + esub;
        int s = ssrc[e];
        float w = sw[e];
        ushort4 g = *(const ushort4*)(hrow + (size_t)s * 64);
        a0 = fmaf(b2f(g.x), w, a0); a1 = fmaf(b2f(g.y), w, a1);
        a2 = fmaf(b2f(g.z), w, a2); a3 = fmaf(b2f(g.w), w, a3);
    }
    if (e0 < dcap) {
        int e = e0 + esub;
        if (e < dcap) {
            int s = ssrc[e];
            float w = sw[e];
            ushort4 g = *(const ushort4*)(hrow + (size_t)s * 64);
            a0 = fmaf(b2f(g.x), w, a0); a1 = fmaf(b2f(g.y), w, a1);
            a2 = fmaf(b2f(g.z), w, a2); a3 = fmaf(b2f(g.w), w, a3);
        }
    }
    for (int j = MAXD + esub; j < deg; j += 4) {
        int s = srcs[beg + j];
        float v = as[s] + adv;
        v = v > 0.f ? v : 0.2f * v;
        float w = __expf(v - vmax) * rden;
        ushort4 g = *(const ushort4*)(hrow + (size_t)s * 64);
        a0 = fmaf(b2f(g.x), w, a0); a1 = fmaf(b2f(g.y), w, a1);
        a2 = fmaf(b2f(g.z), w, a2); a3 = fmaf(b2f(g.w), w, a3);
    }
    a0 += __shfl_xor(a0, 16, 64); a0 += __shfl_xor(a0, 32, 64);
    a1 += __shfl_xor(a1, 16, 64); a1 += __shfl_xor(a1, 32, 64);
    a2 += __shfl_xor(a2, 16, 64); a2 += __shfl_xor(a2, 32, 64);
    a3 += __shfl_xor(a3, 16, 64); a3 += __shfl_xor(a3, 32, 64);
    if (esub == 0) {
        int cb = cg * 4;
        float4 o;
        o.x = a0 + bias[cb + 0];
        o.y = a1 + bias[cb + 1];
        o.z = a2 + bias[cb + 2];
        o.w = a3 + bias[cb + 3];
        *(float4*)&out2[(size_t)d * 64 + cb] = o;
    }
}

// ---------------- pooling ----------------
__global__ void pool_k(const float* __restrict__ h, const int* __restrict__ batch,
                       float* __restrict__ pool, float* __restrict__ cnt, int N) {
    const int NPB = 128;
    int c = threadIdx.x;
    int start = blockIdx.x * NPB;
    int end = min(start + NPB, N);
    float acc = 0.f;
    float cl = 0.f;
    int cur = -1;
    for (int n = start; n < end; ++n) {
        int b = batch[n];
        if (b != cur) {
            if (cur >= 0) {
                atomicAdd(&pool[cur * HID + c], acc);
                if (c == 0) atomicAdd(&cnt[cur], cl);
            }
            cur = b; acc = 0.f; cl = 0.f;
        }
        acc += h[(size_t)n * HID + c];
        cl += 1.f;
    }
    if (cur >= 0) {
        atomicAdd(&pool[cur * HID + c], acc);
        if (c == 0) atomicAdd(&cnt[cur], cl);
    }
}

__global__ void finalize_k(const float* __restrict__ pool, const float* __restrict__ cnt,
                           float* __restrict__ out) {
    int g = blockIdx.x;
    int c = threadIdx.x;
    out[g * HID + c] = pool[g * HID + c] / fmaxf(cnt[g], 1.f);
}

// ---------------- launch ----------------

extern "C" void kernel_launch(void* const* d_in, const int* in_sizes, int n_in,
                              void* d_out, int out_size, void* d_ws, size_t ws_size,
                              hipStream_t stream) {
    const float* x      = (const float*)d_in[0];
    const int*   ei     = (const int*)d_in[1];
    const int*   batch  = (const int*)d_in[2];
    const float* W1     = (const float*)d_in[3];
    const float* a_src1 = (const float*)d_in[4];
    const float* a_dst1 = (const float*)d_in[5];
    const float* b1     = (const float*)d_in[6];
    const float* W2     = (const float*)d_in[7];
    const float* a_src2 = (const float*)d_in[8];
    const float* a_dst2 = (const float*)d_in[9];
    const float* b2     = (const float*)d_in[10];
    float* out = (float*)d_out;

    const int N = in_sizes[0] / 128;    // 50000
    const int E = in_sizes[1] / 2;      // 800000
    const int F1 = 256;
    const int F2 = 64;
    const int NG = 32;
    const int T = E + N;

    // ---- workspace layout (float units) ----
    float* ws = (float*)d_ws;
    size_t o = 0;
    ushort_t* h1b   = (ushort_t*)(ws + o); o += (size_t)N * F1 / 2;
    ushort_t* out1b = (ushort_t*)(ws + o); o += (size_t)N * F1 / 2;
    ushort_t* h2b   = (ushort_t*)(ws + o); o += (size_t)N * F2 / 2;
    float* out2  = ws + o; o += (size_t)N * F2;
    float* asrc1 = ws + o; o += (size_t)N * 4;
    float* adst1 = ws + o; o += (size_t)N * 4;
    float* asrc2 = ws + o; o += (size_t)N;
    float* adst2 = ws + o; o += (size_t)N;
    float* pools = ws + o; o += (size_t)NG * HID;
    float* cnts  = ws + o; o += (size_t)NG;
    ushort_t* W1t = (ushort_t*)(ws + o); o += 256 * 128 / 2;
    ushort_t* W2t = (ushort_t*)(ws + o); o += 64 * 256 / 2;
    int* ib = (int*)(ws + o);
    size_t io = 0;
    int* deg      = ib + io; io += N;
    int* rowstart = ib + io; io += N + 1;
    int* cursor   = ib + io; io += N;
    int* srcs     = ib + io; io += T;
    (void)ws_size; (void)n_in; (void)out_size;

    // ---- weight transposes ----
    transp_k<<<128, 256, 0, stream>>>(W1, W1t, 128, 256);
    transp_k<<<256, 64, 0, stream>>>(W2, W2t, 256, 64);

    // ---- CSR build ----
    fill_i32<<<256, 256, 0, stream>>>(deg, 0, N);
    fill_i32<<<256, 256, 0, stream>>>(cursor, 0, N);
    count_k<<<(T + 255) / 256, 256, 0, stream>>>(ei, E, N, deg);
    scan_k<<<1, 1024, 0, stream>>>(deg, rowstart, N);
    scatter_k<<<(T + 255) / 256, 256, 0, stream>>>(ei, E, N, rowstart, cursor, srcs);

    // ---- layer 1 ----
    gemm_mfma<1, 4, 128, true, false, 4><<<(N + 63) / 64, 256, 0, stream>>>(
        x, W1t, h1b, a_src1, a_dst1, asrc1, adst1, N);
    gat_agg4<<<(N + 3) / 4, 256, 0, stream>>>(h1b, rowstart, srcs, asrc1, adst1, b1, out1b, N);

    // ---- layer 2 ----
    gemm_mfma<2, 1, 256, false, true, 1><<<(N + 127) / 128, 128, 0, stream>>>(
        out1b, W2t, h2b, a_src2, a_dst2, asrc2, adst2, N);
    gat_agg1<<<(N + 3) / 4, 256, 0, stream>>>(h2b, rowstart, srcs, asrc2, adst2, b2, out2, N);

    // ---- pooling ----
    fill_f32<<<8, 256, 0, stream>>>(pools, 0.f, (long)NG * HID);
    fill_f32<<<1, 32, 0, stream>>>(cnts, 0.f, (long)NG);
    pool_k<<<(N + 127) / 128, 64, 0, stream>>>(out2, batch, pools, cnts, N);
    finalize_k<<<NG, HID, 0, stream>>>(pools, cnts, out);
}

// Round 7
// 287.393 us; speedup vs baseline: 5.5838x; 1.2548x over previous
//
#include <hip/hip_runtime.h>
#include <cmath>

#define HID 64
typedef unsigned short ushort_t;
typedef __attribute__((ext_vector_type(8))) short bf16x8;
typedef __attribute__((ext_vector_type(4))) float f32x4;

__device__ inline ushort_t f2b(float f) {
    unsigned u = __float_as_uint(f);
    unsigned r = (u + 0x7fffu + ((u >> 16) & 1u)) >> 16;
    return (ushort_t)r;
}
__device__ inline float b2f(ushort_t b) { return __uint_as_float(((unsigned)b) << 16); }

// ---------------- fills ----------------

__global__ void fill_f32(float* __restrict__ p, float v, long n) {
    long i = (long)blockIdx.x * blockDim.x + threadIdx.x;
    long stride = (long)gridDim.x * blockDim.x;
    for (; i < n; i += stride) p[i] = v;
}

__global__ void fill_i32(int* __restrict__ p, int v, long n) {
    long i = (long)blockIdx.x * blockDim.x + threadIdx.x;
    long stride = (long)gridDim.x * blockDim.x;
    for (; i < n; i += stride) p[i] = v;
}

// ---------------- both weight transposes in one dispatch ----------------
// blocks 0..127: W1 (K=128 -> [256][128]); blocks 128..383: W2 (K=256 -> [64][256])
__global__ __launch_bounds__(256) void transp_both(const float* __restrict__ W1,
                                                   const float* __restrict__ W2,
                                                   ushort_t* __restrict__ W1t,
                                                   ushort_t* __restrict__ W2t) {
    int b = blockIdx.x;
    int t = threadIdx.x;
    if (b < 128) {
        // W1: [128][256] -> W1t [256][128]
        W1t[(size_t)t * 128 + b] = f2b(W1[(size_t)b * 256 + t]);
    } else {
        int k = b - 128;  // 0..255
        if (t < 64)
            W2t[(size_t)t * 256 + k] = f2b(W2[(size_t)k * 64 + t]);
    }
}

// ---------------- MFMA GEMM with fused alpha epilogue ----------------
template<int WM, int WN, int K, bool AF32, bool B_WHOLE, int AH>
__global__ __launch_bounds__(WM * WN * 64) void gemm_mfma(
        const void* __restrict__ Ap, const ushort_t* __restrict__ Bt,
        ushort_t* __restrict__ Cb, const float* __restrict__ a_src,
        const float* __restrict__ a_dst, float* __restrict__ os,
        float* __restrict__ od, int M) {
    constexpr int T = WM * WN * 64;
    constexpr int BM = WM * 64;
    constexpr int BN = WN * 64;
    constexpr int BSTR = B_WHOLE ? (K + 8) : 40;

    __shared__ ushort_t Alds[BM][40];
    __shared__ ushort_t Blds[BN][BSTR];

    const int tid = threadIdx.x;
    const int bm = blockIdx.x * BM;
    const int w = tid >> 6;
    const int l = tid & 63;
    const int lr = l >> 4;
    const int lc = l & 15;
    const int row0 = (WM == 1) ? 0 : w * 64;
    const int col0 = (WN == 1) ? 0 : w * 64;

    f32x4 acc[4][4] = {};

    if (B_WHOLE) {
        constexpr int UPR = K / 8;
        for (int u = tid; u < BN * UPR; u += T) {
            int row = u / UPR, j = u % UPR;
            *(bf16x8*)&Blds[row][j * 8] = *(const bf16x8*)&Bt[(size_t)row * K + j * 8];
        }
    }

    for (int kk = 0; kk < K / 32; ++kk) {
        __syncthreads();
        for (int u = tid; u < BM * 4; u += T) {
            int row = u >> 2, part = u & 3;
            int gm = bm + row;
            bf16x8 v = {0, 0, 0, 0, 0, 0, 0, 0};
            if (gm < M) {
                if (AF32) {
                    const float* ap = (const float*)Ap + (size_t)gm * K + kk * 32 + part * 8;
                    float4 v0 = *(const float4*)ap;
                    float4 v1 = *(const float4*)(ap + 4);
                    v[0] = (short)f2b(v0.x); v[1] = (short)f2b(v0.y);
                    v[2] = (short)f2b(v0.z); v[3] = (short)f2b(v0.w);
                    v[4] = (short)f2b(v1.x); v[5] = (short)f2b(v1.y);
                    v[6] = (short)f2b(v1.z); v[7] = (short)f2b(v1.w);
                } else {
                    v = *(const bf16x8*)((const ushort_t*)Ap + (size_t)gm * K + kk * 32 + part * 8);
                }
            }
            *(bf16x8*)&Alds[row][part * 8] = v;
        }
        if (!B_WHOLE) {
            for (int u = tid; u < BN * 4; u += T) {
                int col = u >> 2, part = u & 3;
                *(bf16x8*)&Blds[col][part * 8] =
                    *(const bf16x8*)&Bt[(size_t)col * K + kk * 32 + part * 8];
            }
        }
        __syncthreads();

        const int koff = B_WHOLE ? kk * 32 : 0;
        bf16x8 af[4], bfr[4];
        #pragma unroll
        for (int fr = 0; fr < 4; ++fr)
            af[fr] = *(const bf16x8*)&Alds[row0 + fr * 16 + lc][lr * 8];
        #pragma unroll
        for (int fc = 0; fc < 4; ++fc)
            bfr[fc] = *(const bf16x8*)&Blds[col0 + fc * 16 + lc][koff + lr * 8];
        #pragma unroll
        for (int fr = 0; fr < 4; ++fr)
            #pragma unroll
            for (int fc = 0; fc < 4; ++fc)
                acc[fr][fc] = __builtin_amdgcn_mfma_f32_16x16x32_bf16(
                    af[fr], bfr[fc], acc[fr][fc], 0, 0, 0);
    }

    #pragma unroll
    for (int fr = 0; fr < 4; ++fr)
        #pragma unroll
        for (int r = 0; r < 4; ++r) {
            int gm = bm + row0 + fr * 16 + lr * 4 + r;
            if (gm >= M) continue;
            #pragma unroll
            for (int fc = 0; fc < 4; ++fc)
                Cb[(size_t)gm * BN + col0 + fc * 16 + lc] = f2b(acc[fr][fc][r]);
        }

    if (AH > 0) {
        const int head = (WN > 1) ? w : 0;
        const float* __restrict__ asv = a_src + head * 64;
        const float* __restrict__ adv = a_dst + head * 64;
        #pragma unroll
        for (int fr = 0; fr < 4; ++fr)
            #pragma unroll
            for (int r = 0; r < 4; ++r) {
                float ps = 0.f, pd = 0.f;
                #pragma unroll
                for (int fc = 0; fc < 4; ++fc) {
                    float av = acc[fr][fc][r];
                    ps = fmaf(av, asv[fc * 16 + lc], ps);
                    pd = fmaf(av, adv[fc * 16 + lc], pd);
                }
                #pragma unroll
                for (int off = 1; off < 16; off <<= 1) {
                    ps += __shfl_xor(ps, off, 64);
                    pd += __shfl_xor(pd, off, 64);
                }
                int gm = bm + row0 + fr * 16 + lr * 4 + r;
                if (lc == 0 && gm < M) {
                    os[(size_t)gm * AH + head] = ps;
                    od[(size_t)gm * AH + head] = pd;
                }
            }
    }
}

// ---------------- CSR build ----------------

__global__ void count_k(const int* __restrict__ ei, int E, int N, int* __restrict__ deg) {
    int e = blockIdx.x * blockDim.x + threadIdx.x;
    int T = E + N;
    if (e >= T) return;
    int d = (e < E) ? ei[E + e] : (e - E);
    atomicAdd(&deg[d], 1);
}

// multi-block scan: phase 1 — per-block sums
__global__ __launch_bounds__(256) void scan1_k(const int* __restrict__ deg,
                                               int* __restrict__ bsum, int N) {
    int i = blockIdx.x * 256 + threadIdx.x;
    int v = (i < N) ? deg[i] : 0;
    #pragma unroll
    for (int off = 32; off > 0; off >>= 1) v += __shfl_xor(v, off, 64);
    __shared__ int ws[4];
    if ((threadIdx.x & 63) == 0) ws[threadIdx.x >> 6] = v;
    __syncthreads();
    if (threadIdx.x == 0) bsum[blockIdx.x] = ws[0] + ws[1] + ws[2] + ws[3];
}

// phase 2 — exclusive scan of block sums (nb <= 256), single block
__global__ __launch_bounds__(256) void scan2_k(int* __restrict__ bsum, int nb) {
    int t = threadIdx.x;
    int lane = t & 63, wave = t >> 6;
    int v = (t < nb) ? bsum[t] : 0;
    int inc = v;
    #pragma unroll
    for (int off = 1; off < 64; off <<= 1) {
        int u = __shfl_up(inc, off, 64);
        if (lane >= off) inc += u;
    }
    __shared__ int wsum[4];
    if (lane == 63) wsum[wave] = inc;
    __syncthreads();
    int woff = 0;
    for (int w = 0; w < wave; ++w) woff += wsum[w];
    if (t < nb) bsum[t] = inc - v + woff;
}

// phase 3 — block-local exclusive scan + block offset
__global__ __launch_bounds__(256) void scan3_k(const int* __restrict__ deg,
                                               const int* __restrict__ bsum,
                                               int* __restrict__ rowstart, int N) {
    int i = blockIdx.x * 256 + threadIdx.x;
    int lane = threadIdx.x & 63, wave = threadIdx.x >> 6;
    int v = (i < N) ? deg[i] : 0;
    int inc = v;
    #pragma unroll
    for (int off = 1; off < 64; off <<= 1) {
        int u = __shfl_up(inc, off, 64);
        if (lane >= off) inc += u;
    }
    __shared__ int wsum[4];
    if (lane == 63) wsum[wave] = inc;
    __syncthreads();
    int woff = bsum[blockIdx.x];
    for (int w = 0; w < wave; ++w) woff += wsum[w];
    int excl = inc - v + woff;
    if (i < N) rowstart[i] = excl;
    if (i == N - 1) rowstart[N] = excl + v;
}

__global__ void scatter_k(const int* __restrict__ ei, int E, int N,
                          const int* __restrict__ rowstart, int* __restrict__ cursor,
                          int* __restrict__ srcs) {
    int e = blockIdx.x * blockDim.x + threadIdx.x;
    int T = E + N;
    if (e >= T) return;
    int s, d;
    if (e < E) { s = ei[e]; d = ei[E + e]; } else { s = e - E; d = s; }
    int p = atomicAdd(&cursor[d], 1);
    srcs[rowstart[d] + p] = s;
}

// ---------------- GAT aggregation, H=4: one wave per destination ----------------
#define MAXD 128
__global__ __launch_bounds__(256) void gat_agg4(const ushort_t* __restrict__ hb,
        const int* __restrict__ rowstart, const int* __restrict__ srcs,
        const float* __restrict__ as, const float* __restrict__ ad,
        const float* __restrict__ bias, ushort_t* __restrict__ outb, int N) {
    __shared__ int ssrc_s[4][MAXD];
    __shared__ float sw_s[4][MAXD][4];
    __shared__ float hstat_s[4][2][4];
    const int wave = threadIdx.x >> 6;
    const int lane = threadIdx.x & 63;
    int d = blockIdx.x * 4 + wave;
    if (d >= N) return;
    int* ssrc = ssrc_s[wave];
    float (*sw)[4] = sw_s[wave];
    int beg = rowstart[d];
    int deg = rowstart[d + 1] - beg;
    int dcap = deg < MAXD ? deg : MAXD;
    for (int i = lane; i < dcap; i += 64) ssrc[i] = srcs[beg + i];

    const int isub = lane >> 2;
    const int hd = lane & 3;
    float adv = ad[d * 4 + hd];
    float vmax = -INFINITY;
    for (int e0 = 0; e0 < deg; e0 += 16) {
        int e = e0 + isub;
        if (e < deg) {
            int s = (e < MAXD) ? ssrc[e] : srcs[beg + e];
            float v = as[s * 4 + hd] + adv;
            v = v > 0.f ? v : 0.2f * v;
            if (e < MAXD) sw[e][hd] = v;
            vmax = fmaxf(vmax, v);
        }
    }
    #pragma unroll
    for (int off = 4; off < 64; off <<= 1) vmax = fmaxf(vmax, __shfl_xor(vmax, off, 64));
    float dsum = 0.f;
    for (int e0 = 0; e0 < deg; e0 += 16) {
        int e = e0 + isub;
        if (e < deg) {
            float v;
            if (e < MAXD) v = sw[e][hd];
            else {
                int s = srcs[beg + e];
                v = as[s * 4 + hd] + adv;
                v = v > 0.f ? v : 0.2f * v;
            }
            float ex = __expf(v - vmax);
            if (e < MAXD) sw[e][hd] = ex;
            dsum += ex;
        }
    }
    #pragma unroll
    for (int off = 4; off < 64; off <<= 1) dsum += __shfl_xor(dsum, off, 64);
    float rden = 1.f / (dsum + 1e-16f);
    for (int e0 = 0; e0 < dcap; e0 += 16) {
        int e = e0 + isub;
        if (e < dcap) sw[e][hd] *= rden;
    }
    if (deg > MAXD && isub == 0) {
        hstat_s[wave][0][hd] = vmax;
        hstat_s[wave][1][hd] = rden;
    }

    const int hd2 = lane >> 4;
    const ushort_t* __restrict__ hrow = hb + (size_t)(lane * 4);
    float a0 = 0.f, a1 = 0.f, a2 = 0.f, a3 = 0.f;
    int e = 0;
    for (; e + 2 <= dcap; e += 2) {
        int s0 = __builtin_amdgcn_readfirstlane(ssrc[e]);
        int s1 = __builtin_amdgcn_readfirstlane(ssrc[e + 1]);
        float w0 = sw[e][hd2], w1 = sw[e + 1][hd2];
        ushort4 g0 = *(const ushort4*)(hrow + (size_t)s0 * 256);
        ushort4 g1 = *(const ushort4*)(hrow + (size_t)s1 * 256);
        a0 = fmaf(b2f(g0.x), w0, a0); a1 = fmaf(b2f(g0.y), w0, a1);
        a2 = fmaf(b2f(g0.z), w0, a2); a3 = fmaf(b2f(g0.w), w0, a3);
        a0 = fmaf(b2f(g1.x), w1, a0); a1 = fmaf(b2f(g1.y), w1, a1);
        a2 = fmaf(b2f(g1.z), w1, a2); a3 = fmaf(b2f(g1.w), w1, a3);
    }
    for (; e < dcap; ++e) {
        int s = __builtin_amdgcn_readfirstlane(ssrc[e]);
        float w = sw[e][hd2];
        ushort4 g = *(const ushort4*)(hrow + (size_t)s * 256);
        a0 = fmaf(b2f(g.x), w, a0); a1 = fmaf(b2f(g.y), w, a1);
        a2 = fmaf(b2f(g.z), w, a2); a3 = fmaf(b2f(g.w), w, a3);
    }
    if (deg > MAXD) {
        float vm2 = hstat_s[wave][0][hd2];
        float rd2 = hstat_s[wave][1][hd2];
        float adv2 = ad[d * 4 + hd2];
        for (int j = MAXD; j < deg; ++j) {
            int s = srcs[beg + j];
            float v = as[s * 4 + hd2] + adv2;
            v = v > 0.f ? v : 0.2f * v;
            float w = __expf(v - vm2) * rd2;
            ushort4 g = *(const ushort4*)(hrow + (size_t)s * 256);
            a0 = fmaf(b2f(g.x), w, a0); a1 = fmaf(b2f(g.y), w, a1);
            a2 = fmaf(b2f(g.z), w, a2); a3 = fmaf(b2f(g.w), w, a3);
        }
    }
    int cb = lane * 4;
    ushort4 ov;
    ov.x = f2b(fmaxf(a0 + bias[cb + 0], 0.f));
    ov.y = f2b(fmaxf(a1 + bias[cb + 1], 0.f));
    ov.z = f2b(fmaxf(a2 + bias[cb + 2], 0.f));
    ov.w = f2b(fmaxf(a3 + bias[cb + 3], 0.f));
    *(ushort4*)&outb[(size_t)d * 256 + cb] = ov;
}

// ---------------- GAT aggregation, H=1 ----------------
__global__ __launch_bounds__(256) void gat_agg1(const ushort_t* __restrict__ hb,
        const int* __restrict__ rowstart, const int* __restrict__ srcs,
        const float* __restrict__ as, const float* __restrict__ ad,
        const float* __restrict__ bias, float* __restrict__ out2, int N) {
    __shared__ int ssrc_s[4][MAXD];
    __shared__ float sw_s[4][MAXD];
    const int wave = threadIdx.x >> 6;
    const int lane = threadIdx.x & 63;
    int d = blockIdx.x * 4 + wave;
    if (d >= N) return;
    int* ssrc = ssrc_s[wave];
    float* sw = sw_s[wave];
    int beg = rowstart[d];
    int deg = rowstart[d + 1] - beg;
    int dcap = deg < MAXD ? deg : MAXD;
    for (int i = lane; i < dcap; i += 64) ssrc[i] = srcs[beg + i];

    float adv = ad[d];
    float vmax = -INFINITY;
    for (int e0 = 0; e0 < deg; e0 += 64) {
        int e = e0 + lane;
        if (e < deg) {
            int s = (e < MAXD) ? ssrc[e] : srcs[beg + e];
            float v = as[s] + adv;
            v = v > 0.f ? v : 0.2f * v;
            if (e < MAXD) sw[e] = v;
            vmax = fmaxf(vmax, v);
        }
    }
    #pragma unroll
    for (int off = 1; off < 64; off <<= 1) vmax = fmaxf(vmax, __shfl_xor(vmax, off, 64));
    float dsum = 0.f;
    for (int e0 = 0; e0 < deg; e0 += 64) {
        int e = e0 + lane;
        if (e < deg) {
            float v;
            if (e < MAXD) v = sw[e];
            else {
                int s = srcs[beg + e];
                v = as[s] + adv;
                v = v > 0.f ? v : 0.2f * v;
            }
            float ex = __expf(v - vmax);
            if (e < MAXD) sw[e] = ex;
            dsum += ex;
        }
    }
    #pragma unroll
    for (int off = 1; off < 64; off <<= 1) dsum += __shfl_xor(dsum, off, 64);
    float rden = 1.f / (dsum + 1e-16f);
    for (int e0 = 0; e0 < dcap; e0 += 64) {
        int e = e0 + lane;
        if (e < dcap) sw[e] *= rden;
    }

    const int esub = lane >> 4;
    const int cg = lane & 15;
    const ushort_t* __restrict__ hrow = hb + (size_t)(cg * 4);
    float a0 = 0.f, a1 = 0.f, a2 = 0.f, a3 = 0.f;
    int e0 = 0;
    for (; e0 + 4 <= dcap; e0 += 4) {
        int e = e0 + esub;
        int s = ssrc[e];
        float w = sw[e];
        ushort4 g = *(const ushort4*)(hrow + (size_t)s * 64);
        a0 = fmaf(b2f(g.x), w, a0); a1 = fmaf(b2f(g.y), w, a1);
        a2 = fmaf(b2f(g.z), w, a2); a3 = fmaf(b2f(g.w), w, a3);
    }
    if (e0 < dcap) {
        int e = e0 + esub;
        if (e < dcap) {
            int s = ssrc[e];
            float w = sw[e];
            ushort4 g = *(const ushort4*)(hrow + (size_t)s * 64);
            a0 = fmaf(b2f(g.x), w, a0); a1 = fmaf(b2f(g.y), w, a1);
            a2 = fmaf(b2f(g.z), w, a2); a3 = fmaf(b2f(g.w), w, a3);
        }
    }
    for (int j = MAXD + esub; j < deg; j += 4) {
        int s = srcs[beg + j];
        float v = as[s] + adv;
        v = v > 0.f ? v : 0.2f * v;
        float w = __expf(v - vmax) * rden;
        ushort4 g = *(const ushort4*)(hrow + (size_t)s * 64);
        a0 = fmaf(b2f(g.x), w, a0); a1 = fmaf(b2f(g.y), w, a1);
        a2 = fmaf(b2f(g.z), w, a2); a3 = fmaf(b2f(g.w), w, a3);
    }
    a0 += __shfl_xor(a0, 16, 64); a0 += __shfl_xor(a0, 32, 64);
    a1 += __shfl_xor(a1, 16, 64); a1 += __shfl_xor(a1, 32, 64);
    a2 += __shfl_xor(a2, 16, 64); a2 += __shfl_xor(a2, 32, 64);
    a3 += __shfl_xor(a3, 16, 64); a3 += __shfl_xor(a3, 32, 64);
    if (esub == 0) {
        int cb = cg * 4;
        float4 o;
        o.x = a0 + bias[cb + 0];
        o.y = a1 + bias[cb + 1];
        o.z = a2 + bias[cb + 2];
        o.w = a3 + bias[cb + 3];
        *(float4*)&out2[(size_t)d * 64 + cb] = o;
    }
}

// ---------------- pooling ----------------
__global__ void pool_k(const float* __restrict__ h, const int* __restrict__ batch,
                       float* __restrict__ pool, float* __restrict__ cnt, int N) {
    const int NPB = 128;
    int c = threadIdx.x;
    int start = blockIdx.x * NPB;
    int end = min(start + NPB, N);
    float acc = 0.f;
    float cl = 0.f;
    int cur = -1;
    for (int n = start; n < end; ++n) {
        int b = batch[n];
        if (b != cur) {
            if (cur >= 0) {
                atomicAdd(&pool[cur * HID + c], acc);
                if (c == 0) atomicAdd(&cnt[cur], cl);
            }
            cur = b; acc = 0.f; cl = 0.f;
        }
        acc += h[(size_t)n * HID + c];
        cl += 1.f;
    }
    if (cur >= 0) {
        atomicAdd(&pool[cur * HID + c], acc);
        if (c == 0) atomicAdd(&cnt[cur], cl);
    }
}

__global__ void finalize_k(const float* __restrict__ pool, const float* __restrict__ cnt,
                           float* __restrict__ out) {
    int g = blockIdx.x;
    int c = threadIdx.x;
    out[g * HID + c] = pool[g * HID + c] / fmaxf(cnt[g], 1.f);
}

// ---------------- launch ----------------

extern "C" void kernel_launch(void* const* d_in, const int* in_sizes, int n_in,
                              void* d_out, int out_size, void* d_ws, size_t ws_size,
                              hipStream_t stream) {
    const float* x      = (const float*)d_in[0];
    const int*   ei     = (const int*)d_in[1];
    const int*   batch  = (const int*)d_in[2];
    const float* W1     = (const float*)d_in[3];
    const float* a_src1 = (const float*)d_in[4];
    const float* a_dst1 = (const float*)d_in[5];
    const float* b1     = (const float*)d_in[6];
    const float* W2     = (const float*)d_in[7];
    const float* a_src2 = (const float*)d_in[8];
    const float* a_dst2 = (const float*)d_in[9];
    const float* b2     = (const float*)d_in[10];
    float* out = (float*)d_out;

    const int N = in_sizes[0] / 128;    // 50000
    const int E = in_sizes[1] / 2;      // 800000
    const int F1 = 256;
    const int F2 = 64;
    const int NG = 32;
    const int T = E + N;
    const int NB = (N + 255) / 256;     // scan blocks (196)

    // ---- workspace layout (float units) ----
    float* ws = (float*)d_ws;
    size_t o = 0;
    ushort_t* h1b   = (ushort_t*)(ws + o); o += (size_t)N * F1 / 2;
    ushort_t* out1b = (ushort_t*)(ws + o); o += (size_t)N * F1 / 2;
    ushort_t* h2b   = (ushort_t*)(ws + o); o += (size_t)N * F2 / 2;
    float* out2  = ws + o; o += (size_t)N * F2;
    float* asrc1 = ws + o; o += (size_t)N * 4;
    float* adst1 = ws + o; o += (size_t)N * 4;
    float* asrc2 = ws + o; o += (size_t)N;
    float* adst2 = ws + o; o += (size_t)N;
    float* pools = ws + o; o += (size_t)NG * HID;   // pools+cnts contiguous
    float* cnts  = ws + o; o += (size_t)NG;
    ushort_t* W1t = (ushort_t*)(ws + o); o += 256 * 128 / 2;
    ushort_t* W2t = (ushort_t*)(ws + o); o += 64 * 256 / 2;
    int* ib = (int*)(ws + o);
    size_t io = 0;
    int* deg      = ib + io; io += N;      // deg+cursor contiguous -> one fill
    int* cursor   = ib + io; io += N;
    int* rowstart = ib + io; io += N + 1;
    int* bsum     = ib + io; io += NB;
    int* srcs     = ib + io; io += T;
    (void)ws_size; (void)n_in; (void)out_size;

    // ---- weight transposes (one dispatch) ----
    transp_both<<<384, 256, 0, stream>>>(W1, W2, W1t, W2t);

    // ---- CSR build ----
    fill_i32<<<256, 256, 0, stream>>>(deg, 0, 2L * N);
    count_k<<<(T + 255) / 256, 256, 0, stream>>>(ei, E, N, deg);
    scan1_k<<<NB, 256, 0, stream>>>(deg, bsum, N);
    scan2_k<<<1, 256, 0, stream>>>(bsum, NB);
    scan3_k<<<NB, 256, 0, stream>>>(deg, bsum, rowstart, N);
    scatter_k<<<(T + 255) / 256, 256, 0, stream>>>(ei, E, N, rowstart, cursor, srcs);

    // ---- layer 1 ----
    gemm_mfma<1, 4, 128, true, false, 4><<<(N + 63) / 64, 256, 0, stream>>>(
        x, W1t, h1b, a_src1, a_dst1, asrc1, adst1, N);
    gat_agg4<<<(N + 3) / 4, 256, 0, stream>>>(h1b, rowstart, srcs, asrc1, adst1, b1, out1b, N);

    // ---- layer 2 ----
    gemm_mfma<2, 1, 256, false, true, 1><<<(N + 127) / 128, 128, 0, stream>>>(
        out1b, W2t, h2b, a_src2, a_dst2, asrc2, adst2, N);
    gat_agg1<<<(N + 3) / 4, 256, 0, stream>>>(h2b, rowstart, srcs, asrc2, adst2, b2, out2, N);

    // ---- pooling (pools+cnts zeroed in one fill) ----
    fill_f32<<<8, 256, 0, stream>>>(pools, 0.f, (long)NG * HID + NG);
    pool_k<<<(N + 127) / 128, 64, 0, stream>>>(out2, batch, pools, cnts, N);
    finalize_k<<<NG, HID, 0, stream>>>(pools, cnts, out);
}

// Round 8
// 256.145 us; speedup vs baseline: 6.2649x; 1.1220x over previous
//
#include <hip/hip_runtime.h>
#include <cmath>

#define HID 64
typedef unsigned short ushort_t;
typedef __attribute__((ext_vector_type(8))) short bf16x8;
typedef __attribute__((ext_vector_type(4))) float f32x4;

__device__ inline ushort_t f2b(float f) {
    unsigned u = __float_as_uint(f);
    unsigned r = (u + 0x7fffu + ((u >> 16) & 1u)) >> 16;
    return (ushort_t)r;
}
__device__ inline float b2f(ushort_t b) { return __uint_as_float(((unsigned)b) << 16); }

// ---------------- fills ----------------

__global__ void fill_i32(int* __restrict__ p, int v, long n) {
    long i = (long)blockIdx.x * blockDim.x + threadIdx.x;
    long stride = (long)gridDim.x * blockDim.x;
    for (; i < n; i += stride) p[i] = v;
}

// ---------------- prep: weight transposes + batch histogram + zero d_out ----------
// blocks [0,128): W1t; [128,384): W2t; [384,384+NHB): batch histogram; last: zero out
__global__ __launch_bounds__(256) void prep_k(const float* __restrict__ W1,
                                              const float* __restrict__ W2,
                                              ushort_t* __restrict__ W1t,
                                              ushort_t* __restrict__ W2t,
                                              const int* __restrict__ batch,
                                              int* __restrict__ cnt_i,
                                              float* __restrict__ outp,
                                              int N, int NHB) {
    int b = blockIdx.x;
    int t = threadIdx.x;
    if (b < 128) {
        W1t[(size_t)t * 128 + b] = f2b(W1[(size_t)b * 256 + t]);
    } else if (b < 384) {
        int k = b - 128;
        if (t < 64) W2t[(size_t)t * 256 + k] = f2b(W2[(size_t)k * 64 + t]);
    } else if (b < 384 + NHB) {
        __shared__ int lh[32];
        if (t < 32) lh[t] = 0;
        __syncthreads();
        int i = (b - 384) * 256 + t;
        if (i < N) atomicAdd(&lh[batch[i]], 1);
        __syncthreads();
        if (t < 32 && lh[t] > 0) atomicAdd(&cnt_i[t], lh[t]);
    } else {
        int i = t * 8;
        #pragma unroll
        for (int j = 0; j < 8; ++j) outp[i + j] = 0.f;
    }
}

// ---------------- MFMA GEMM with fused alpha epilogue ----------------
template<int WM, int WN, int K, bool AF32, bool B_WHOLE, int AH>
__global__ __launch_bounds__(WM * WN * 64) void gemm_mfma(
        const void* __restrict__ Ap, const ushort_t* __restrict__ Bt,
        ushort_t* __restrict__ Cb, const float* __restrict__ a_src,
        const float* __restrict__ a_dst, float* __restrict__ os,
        float* __restrict__ od, int M) {
    constexpr int T = WM * WN * 64;
    constexpr int BM = WM * 64;
    constexpr int BN = WN * 64;
    constexpr int BSTR = B_WHOLE ? (K + 8) : 40;

    __shared__ ushort_t Alds[BM][40];
    __shared__ ushort_t Blds[BN][BSTR];

    const int tid = threadIdx.x;
    const int bm = blockIdx.x * BM;
    const int w = tid >> 6;
    const int l = tid & 63;
    const int lr = l >> 4;
    const int lc = l & 15;
    const int row0 = (WM == 1) ? 0 : w * 64;
    const int col0 = (WN == 1) ? 0 : w * 64;

    f32x4 acc[4][4] = {};

    if (B_WHOLE) {
        constexpr int UPR = K / 8;
        for (int u = tid; u < BN * UPR; u += T) {
            int row = u / UPR, j = u % UPR;
            *(bf16x8*)&Blds[row][j * 8] = *(const bf16x8*)&Bt[(size_t)row * K + j * 8];
        }
    }

    for (int kk = 0; kk < K / 32; ++kk) {
        __syncthreads();
        for (int u = tid; u < BM * 4; u += T) {
            int row = u >> 2, part = u & 3;
            int gm = bm + row;
            bf16x8 v = {0, 0, 0, 0, 0, 0, 0, 0};
            if (gm < M) {
                if (AF32) {
                    const float* ap = (const float*)Ap + (size_t)gm * K + kk * 32 + part * 8;
                    float4 v0 = *(const float4*)ap;
                    float4 v1 = *(const float4*)(ap + 4);
                    v[0] = (short)f2b(v0.x); v[1] = (short)f2b(v0.y);
                    v[2] = (short)f2b(v0.z); v[3] = (short)f2b(v0.w);
                    v[4] = (short)f2b(v1.x); v[5] = (short)f2b(v1.y);
                    v[6] = (short)f2b(v1.z); v[7] = (short)f2b(v1.w);
                } else {
                    v = *(const bf16x8*)((const ushort_t*)Ap + (size_t)gm * K + kk * 32 + part * 8);
                }
            }
            *(bf16x8*)&Alds[row][part * 8] = v;
        }
        if (!B_WHOLE) {
            for (int u = tid; u < BN * 4; u += T) {
                int col = u >> 2, part = u & 3;
                *(bf16x8*)&Blds[col][part * 8] =
                    *(const bf16x8*)&Bt[(size_t)col * K + kk * 32 + part * 8];
            }
        }
        __syncthreads();

        const int koff = B_WHOLE ? kk * 32 : 0;
        bf16x8 af[4], bfr[4];
        #pragma unroll
        for (int fr = 0; fr < 4; ++fr)
            af[fr] = *(const bf16x8*)&Alds[row0 + fr * 16 + lc][lr * 8];
        #pragma unroll
        for (int fc = 0; fc < 4; ++fc)
            bfr[fc] = *(const bf16x8*)&Blds[col0 + fc * 16 + lc][koff + lr * 8];
        #pragma unroll
        for (int fr = 0; fr < 4; ++fr)
            #pragma unroll
            for (int fc = 0; fc < 4; ++fc)
                acc[fr][fc] = __builtin_amdgcn_mfma_f32_16x16x32_bf16(
                    af[fr], bfr[fc], acc[fr][fc], 0, 0, 0);
    }

    #pragma unroll
    for (int fr = 0; fr < 4; ++fr)
        #pragma unroll
        for (int r = 0; r < 4; ++r) {
            int gm = bm + row0 + fr * 16 + lr * 4 + r;
            if (gm >= M) continue;
            #pragma unroll
            for (int fc = 0; fc < 4; ++fc)
                Cb[(size_t)gm * BN + col0 + fc * 16 + lc] = f2b(acc[fr][fc][r]);
        }

    if (AH > 0) {
        const int head = (WN > 1) ? w : 0;
        const float* __restrict__ asv = a_src + head * 64;
        const float* __restrict__ adv = a_dst + head * 64;
        #pragma unroll
        for (int fr = 0; fr < 4; ++fr)
            #pragma unroll
            for (int r = 0; r < 4; ++r) {
                float ps = 0.f, pd = 0.f;
                #pragma unroll
                for (int fc = 0; fc < 4; ++fc) {
                    float av = acc[fr][fc][r];
                    ps = fmaf(av, asv[fc * 16 + lc], ps);
                    pd = fmaf(av, adv[fc * 16 + lc], pd);
                }
                #pragma unroll
                for (int off = 1; off < 16; off <<= 1) {
                    ps += __shfl_xor(ps, off, 64);
                    pd += __shfl_xor(pd, off, 64);
                }
                int gm = bm + row0 + fr * 16 + lr * 4 + r;
                if (lc == 0 && gm < M) {
                    os[(size_t)gm * AH + head] = ps;
                    od[(size_t)gm * AH + head] = pd;
                }
            }
    }
}

// ---------------- CSR build ----------------

__global__ void count_k(const int* __restrict__ ei, int E, int N, int* __restrict__ deg) {
    int e = blockIdx.x * blockDim.x + threadIdx.x;
    int T = E + N;
    if (e >= T) return;
    int d = (e < E) ? ei[E + e] : (e - E);
    atomicAdd(&deg[d], 1);
}

// phase 1 — per-block sums
__global__ __launch_bounds__(256) void scan1_k(const int* __restrict__ deg,
                                               int* __restrict__ bsum, int N) {
    int i = blockIdx.x * 256 + threadIdx.x;
    int v = (i < N) ? deg[i] : 0;
    #pragma unroll
    for (int off = 32; off > 0; off >>= 1) v += __shfl_xor(v, off, 64);
    __shared__ int ws[4];
    if ((threadIdx.x & 63) == 0) ws[threadIdx.x >> 6] = v;
    __syncthreads();
    if (threadIdx.x == 0) bsum[blockIdx.x] = ws[0] + ws[1] + ws[2] + ws[3];
}

// phase 2 — block-local exclusive scan; inline prefix of bsum (NB <= 256)
__global__ __launch_bounds__(256) void scan3_k(const int* __restrict__ deg,
                                               const int* __restrict__ bsum,
                                               int* __restrict__ rowstart, int N, int NB) {
    int t = threadIdx.x;
    int lane = t & 63, wave = t >> 6;
    // inclusive-over-previous-blocks base: sum of bsum[0 .. blockIdx.x)
    int pv = (t < NB && t < (int)blockIdx.x) ? bsum[t] : 0;
    #pragma unroll
    for (int off = 32; off > 0; off >>= 1) pv += __shfl_xor(pv, off, 64);
    __shared__ int wsp[4];
    if (lane == 0) wsp[wave] = pv;
    __syncthreads();
    int base = wsp[0] + wsp[1] + wsp[2] + wsp[3];

    int i = blockIdx.x * 256 + t;
    int v = (i < N) ? deg[i] : 0;
    int inc = v;
    #pragma unroll
    for (int off = 1; off < 64; off <<= 1) {
        int u = __shfl_up(inc, off, 64);
        if (lane >= off) inc += u;
    }
    __shared__ int wsum[4];
    if (lane == 63) wsum[wave] = inc;
    __syncthreads();
    int woff = base;
    for (int w = 0; w < wave; ++w) woff += wsum[w];
    int excl = inc - v + woff;
    if (i < N) rowstart[i] = excl;
    if (i == N - 1) rowstart[N] = excl + v;
}

__global__ void scatter_k(const int* __restrict__ ei, int E, int N,
                          const int* __restrict__ rowstart, int* __restrict__ cursor,
                          int* __restrict__ srcs) {
    int e = blockIdx.x * blockDim.x + threadIdx.x;
    int T = E + N;
    if (e >= T) return;
    int s, d;
    if (e < E) { s = ei[e]; d = ei[E + e]; } else { s = e - E; d = s; }
    int p = atomicAdd(&cursor[d], 1);
    srcs[rowstart[d] + p] = s;
}

// ---------------- GAT aggregation, H=4: one wave per destination ----------------
#define MAXD 128
__global__ __launch_bounds__(256) void gat_agg4(const ushort_t* __restrict__ hb,
        const int* __restrict__ rowstart, const int* __restrict__ srcs,
        const float* __restrict__ as, const float* __restrict__ ad,
        const float* __restrict__ bias, ushort_t* __restrict__ outb, int N) {
    __shared__ int ssrc_s[4][MAXD];
    __shared__ float sw_s[4][MAXD][4];
    __shared__ float hstat_s[4][2][4];
    const int wave = threadIdx.x >> 6;
    const int lane = threadIdx.x & 63;
    int d = blockIdx.x * 4 + wave;
    if (d >= N) return;
    int* ssrc = ssrc_s[wave];
    float (*sw)[4] = sw_s[wave];
    int beg = rowstart[d];
    int deg = rowstart[d + 1] - beg;
    int dcap = deg < MAXD ? deg : MAXD;
    for (int i = lane; i < dcap; i += 64) ssrc[i] = srcs[beg + i];

    const int isub = lane >> 2;
    const int hd = lane & 3;
    float adv = ad[d * 4 + hd];
    float vmax = -INFINITY;
    for (int e0 = 0; e0 < deg; e0 += 16) {
        int e = e0 + isub;
        if (e < deg) {
            int s = (e < MAXD) ? ssrc[e] : srcs[beg + e];
            float v = as[s * 4 + hd] + adv;
            v = v > 0.f ? v : 0.2f * v;
            if (e < MAXD) sw[e][hd] = v;
            vmax = fmaxf(vmax, v);
        }
    }
    #pragma unroll
    for (int off = 4; off < 64; off <<= 1) vmax = fmaxf(vmax, __shfl_xor(vmax, off, 64));
    float dsum = 0.f;
    for (int e0 = 0; e0 < deg; e0 += 16) {
        int e = e0 + isub;
        if (e < deg) {
            float v;
            if (e < MAXD) v = sw[e][hd];
            else {
                int s = srcs[beg + e];
                v = as[s * 4 + hd] + adv;
                v = v > 0.f ? v : 0.2f * v;
            }
            float ex = __expf(v - vmax);
            if (e < MAXD) sw[e][hd] = ex;
            dsum += ex;
        }
    }
    #pragma unroll
    for (int off = 4; off < 64; off <<= 1) dsum += __shfl_xor(dsum, off, 64);
    float rden = 1.f / (dsum + 1e-16f);
    for (int e0 = 0; e0 < dcap; e0 += 16) {
        int e = e0 + isub;
        if (e < dcap) sw[e][hd] *= rden;
    }
    if (deg > MAXD && isub == 0) {
        hstat_s[wave][0][hd] = vmax;
        hstat_s[wave][1][hd] = rden;
    }

    // phase 2: 4-edge unroll, 4 gathers in flight
    const int hd2 = lane >> 4;
    const ushort_t* __restrict__ hrow = hb + (size_t)(lane * 4);
    float a0 = 0.f, a1 = 0.f, a2 = 0.f, a3 = 0.f;
    int e = 0;
    for (; e + 4 <= dcap; e += 4) {
        int s0 = __builtin_amdgcn_readfirstlane(ssrc[e]);
        int s1 = __builtin_amdgcn_readfirstlane(ssrc[e + 1]);
        int s2 = __builtin_amdgcn_readfirstlane(ssrc[e + 2]);
        int s3 = __builtin_amdgcn_readfirstlane(ssrc[e + 3]);
        ushort4 g0 = *(const ushort4*)(hrow + (size_t)s0 * 256);
        ushort4 g1 = *(const ushort4*)(hrow + (size_t)s1 * 256);
        ushort4 g2 = *(const ushort4*)(hrow + (size_t)s2 * 256);
        ushort4 g3 = *(const ushort4*)(hrow + (size_t)s3 * 256);
        float w0 = sw[e][hd2], w1 = sw[e + 1][hd2];
        float w2 = sw[e + 2][hd2], w3 = sw[e + 3][hd2];
        a0 = fmaf(b2f(g0.x), w0, a0); a1 = fmaf(b2f(g0.y), w0, a1);
        a2 = fmaf(b2f(g0.z), w0, a2); a3 = fmaf(b2f(g0.w), w0, a3);
        a0 = fmaf(b2f(g1.x), w1, a0); a1 = fmaf(b2f(g1.y), w1, a1);
        a2 = fmaf(b2f(g1.z), w1, a2); a3 = fmaf(b2f(g1.w), w1, a3);
        a0 = fmaf(b2f(g2.x), w2, a0); a1 = fmaf(b2f(g2.y), w2, a1);
        a2 = fmaf(b2f(g2.z), w2, a2); a3 = fmaf(b2f(g2.w), w2, a3);
        a0 = fmaf(b2f(g3.x), w3, a0); a1 = fmaf(b2f(g3.y), w3, a1);
        a2 = fmaf(b2f(g3.z), w3, a2); a3 = fmaf(b2f(g3.w), w3, a3);
    }
    for (; e < dcap; ++e) {
        int s = __builtin_amdgcn_readfirstlane(ssrc[e]);
        float w = sw[e][hd2];
        ushort4 g = *(const ushort4*)(hrow + (size_t)s * 256);
        a0 = fmaf(b2f(g.x), w, a0); a1 = fmaf(b2f(g.y), w, a1);
        a2 = fmaf(b2f(g.z), w, a2); a3 = fmaf(b2f(g.w), w, a3);
    }
    if (deg > MAXD) {
        float vm2 = hstat_s[wave][0][hd2];
        float rd2 = hstat_s[wave][1][hd2];
        float adv2 = ad[d * 4 + hd2];
        for (int j = MAXD; j < deg; ++j) {
            int s = srcs[beg + j];
            float v = as[s * 4 + hd2] + adv2;
            v = v > 0.f ? v : 0.2f * v;
            float w = __expf(v - vm2) * rd2;
            ushort4 g = *(const ushort4*)(hrow + (size_t)s * 256);
            a0 = fmaf(b2f(g.x), w, a0); a1 = fmaf(b2f(g.y), w, a1);
            a2 = fmaf(b2f(g.z), w, a2); a3 = fmaf(b2f(g.w), w, a3);
        }
    }
    int cb = lane * 4;
    ushort4 ov;
    ov.x = f2b(fmaxf(a0 + bias[cb + 0], 0.f));
    ov.y = f2b(fmaxf(a1 + bias[cb + 1], 0.f));
    ov.z = f2b(fmaxf(a2 + bias[cb + 2], 0.f));
    ov.w = f2b(fmaxf(a3 + bias[cb + 3], 0.f));
    *(ushort4*)&outb[(size_t)d * 256 + cb] = ov;
}

// ---------------- GAT aggregation H=1 with fused mean-pool into d_out ----------
__global__ __launch_bounds__(256) void gat_agg1(const ushort_t* __restrict__ hb,
        const int* __restrict__ rowstart, const int* __restrict__ srcs,
        const float* __restrict__ as, const float* __restrict__ ad,
        const float* __restrict__ bias, const int* __restrict__ batch,
        const int* __restrict__ cnt_i, float* __restrict__ outp, int N) {
    __shared__ int ssrc_s[4][MAXD];
    __shared__ float sw_s[4][MAXD];
    __shared__ float prow[4][64];
    __shared__ int gws[4];
    const int wave = threadIdx.x >> 6;
    const int lane = threadIdx.x & 63;
    int d = blockIdx.x * 4 + wave;
    bool active = d < N;
    if (active) {
        int* ssrc = ssrc_s[wave];
        float* sw = sw_s[wave];
        int beg = rowstart[d];
        int deg = rowstart[d + 1] - beg;
        int dcap = deg < MAXD ? deg : MAXD;
        for (int i = lane; i < dcap; i += 64) ssrc[i] = srcs[beg + i];

        float adv = ad[d];
        float vmax = -INFINITY;
        for (int e0 = 0; e0 < deg; e0 += 64) {
            int e = e0 + lane;
            if (e < deg) {
                int s = (e < MAXD) ? ssrc[e] : srcs[beg + e];
                float v = as[s] + adv;
                v = v > 0.f ? v : 0.2f * v;
                if (e < MAXD) sw[e] = v;
                vmax = fmaxf(vmax, v);
            }
        }
        #pragma unroll
        for (int off = 1; off < 64; off <<= 1) vmax = fmaxf(vmax, __shfl_xor(vmax, off, 64));
        float dsum = 0.f;
        for (int e0 = 0; e0 < deg; e0 += 64) {
            int e = e0 + lane;
            if (e < deg) {
                float v;
                if (e < MAXD) v = sw[e];
                else {
                    int s = srcs[beg + e];
                    v = as[s] + adv;
                    v = v > 0.f ? v : 0.2f * v;
                }
                float ex = __expf(v - vmax);
                if (e < MAXD) sw[e] = ex;
                dsum += ex;
            }
        }
        #pragma unroll
        for (int off = 1; off < 64; off <<= 1) dsum += __shfl_xor(dsum, off, 64);
        float rden = 1.f / (dsum + 1e-16f);
        for (int e0 = 0; e0 < dcap; e0 += 64) {
            int e = e0 + lane;
            if (e < dcap) sw[e] *= rden;
        }

        const int esub = lane >> 4;
        const int cg = lane & 15;
        const ushort_t* __restrict__ hrow = hb + (size_t)(cg * 4);
        float a0 = 0.f, a1 = 0.f, a2 = 0.f, a3 = 0.f;
        int e0 = 0;
        for (; e0 + 4 <= dcap; e0 += 4) {
            int e = e0 + esub;
            int s = ssrc[e];
            float w = sw[e];
            ushort4 g = *(const ushort4*)(hrow + (size_t)s * 64);
            a0 = fmaf(b2f(g.x), w, a0); a1 = fmaf(b2f(g.y), w, a1);
            a2 = fmaf(b2f(g.z), w, a2); a3 = fmaf(b2f(g.w), w, a3);
        }
        if (e0 < dcap) {
            int e = e0 + esub;
            if (e < dcap) {
                int s = ssrc[e];
                float w = sw[e];
                ushort4 g = *(const ushort4*)(hrow + (size_t)s * 64);
                a0 = fmaf(b2f(g.x), w, a0); a1 = fmaf(b2f(g.y), w, a1);
                a2 = fmaf(b2f(g.z), w, a2); a3 = fmaf(b2f(g.w), w, a3);
            }
        }
        for (int j = MAXD + esub; j < deg; j += 4) {
            int s = srcs[beg + j];
            float v = as[s] + adv;
            v = v > 0.f ? v : 0.2f * v;
            float w = __expf(v - vmax) * rden;
            ushort4 g = *(const ushort4*)(hrow + (size_t)s * 64);
            a0 = fmaf(b2f(g.x), w, a0); a1 = fmaf(b2f(g.y), w, a1);
            a2 = fmaf(b2f(g.z), w, a2); a3 = fmaf(b2f(g.w), w, a3);
        }
        a0 += __shfl_xor(a0, 16, 64); a0 += __shfl_xor(a0, 32, 64);
        a1 += __shfl_xor(a1, 16, 64); a1 += __shfl_xor(a1, 32, 64);
        a2 += __shfl_xor(a2, 16, 64); a2 += __shfl_xor(a2, 32, 64);
        a3 += __shfl_xor(a3, 16, 64); a3 += __shfl_xor(a3, 32, 64);
        int g = batch[d];
        if (esub == 0) {
            float cntf = fmaxf((float)cnt_i[g], 1.f);
            float rc = 1.f / cntf;
            int cb = cg * 4;
            float4 o;
            o.x = (a0 + bias[cb + 0]) * rc;
            o.y = (a1 + bias[cb + 1]) * rc;
            o.z = (a2 + bias[cb + 2]) * rc;
            o.w = (a3 + bias[cb + 3]) * rc;
            *(float4*)&prow[wave][cb] = o;
        }
        if (lane == 0) gws[wave] = g;
    } else {
        if (lane == 0) gws[wave] = -1;
    }
    __syncthreads();
    if (threadIdx.x < 64) {
        int t = threadIdx.x;
        int g0 = gws[0];
        if (g0 >= 0 && gws[1] == g0 && gws[2] == g0 && gws[3] == g0) {
            atomicAdd(&outp[g0 * 64 + t],
                      prow[0][t] + prow[1][t] + prow[2][t] + prow[3][t]);
        } else {
            #pragma unroll
            for (int w2 = 0; w2 < 4; ++w2)
                if (gws[w2] >= 0) atomicAdd(&outp[gws[w2] * 64 + t], prow[w2][t]);
        }
    }
}

// ---------------- launch ----------------

extern "C" void kernel_launch(void* const* d_in, const int* in_sizes, int n_in,
                              void* d_out, int out_size, void* d_ws, size_t ws_size,
                              hipStream_t stream) {
    const float* x      = (const float*)d_in[0];
    const int*   ei     = (const int*)d_in[1];
    const int*   batch  = (const int*)d_in[2];
    const float* W1     = (const float*)d_in[3];
    const float* a_src1 = (const float*)d_in[4];
    const float* a_dst1 = (const float*)d_in[5];
    const float* b1     = (const float*)d_in[6];
    const float* W2     = (const float*)d_in[7];
    const float* a_src2 = (const float*)d_in[8];
    const float* a_dst2 = (const float*)d_in[9];
    const float* b2     = (const float*)d_in[10];
    float* out = (float*)d_out;

    const int N = in_sizes[0] / 128;    // 50000
    const int E = in_sizes[1] / 2;      // 800000
    const int F1 = 256;
    const int F2 = 64;
    const int T = E + N;
    const int NB = (N + 255) / 256;     // scan/hist blocks (196)

    // ---- workspace layout (float units) ----
    float* ws = (float*)d_ws;
    size_t o = 0;
    ushort_t* h1b   = (ushort_t*)(ws + o); o += (size_t)N * F1 / 2;
    ushort_t* out1b = (ushort_t*)(ws + o); o += (size_t)N * F1 / 2;
    ushort_t* h2b   = (ushort_t*)(ws + o); o += (size_t)N * F2 / 2;
    float* asrc1 = ws + o; o += (size_t)N * 4;
    float* adst1 = ws + o; o += (size_t)N * 4;
    float* asrc2 = ws + o; o += (size_t)N;
    float* adst2 = ws + o; o += (size_t)N;
    ushort_t* W1t = (ushort_t*)(ws + o); o += 256 * 128 / 2;
    ushort_t* W2t = (ushort_t*)(ws + o); o += 64 * 256 / 2;
    int* ib = (int*)(ws + o);
    size_t io = 0;
    int* deg      = ib + io; io += N;      // deg+cursor+cnt contiguous -> one fill
    int* cursor   = ib + io; io += N;
    int* cnt_i    = ib + io; io += 32;
    int* rowstart = ib + io; io += N + 1;
    int* bsum     = ib + io; io += NB;
    int* srcs     = ib + io; io += T;
    (void)ws_size; (void)n_in; (void)out_size;

    // ---- zero counters, then prep (transposes + batch hist + zero d_out) ----
    fill_i32<<<256, 256, 0, stream>>>(deg, 0, 2L * N + 32);
    prep_k<<<384 + NB + 1, 256, 0, stream>>>(W1, W2, W1t, W2t, batch, cnt_i, out, N, NB);

    // ---- CSR build ----
    count_k<<<(T + 255) / 256, 256, 0, stream>>>(ei, E, N, deg);
    scan1_k<<<NB, 256, 0, stream>>>(deg, bsum, N);
    scan3_k<<<NB, 256, 0, stream>>>(deg, bsum, rowstart, N, NB);
    scatter_k<<<(T + 255) / 256, 256, 0, stream>>>(ei, E, N, rowstart, cursor, srcs);

    // ---- layer 1 ----
    gemm_mfma<1, 4, 128, true, false, 4><<<(N + 63) / 64, 256, 0, stream>>>(
        x, W1t, h1b, a_src1, a_dst1, asrc1, adst1, N);
    gat_agg4<<<(N + 3) / 4, 256, 0, stream>>>(h1b, rowstart, srcs, asrc1, adst1, b1, out1b, N);

    // ---- layer 2 (+ fused mean pool) ----
    gemm_mfma<2, 1, 256, false, true, 1><<<(N + 127) / 128, 128, 0, stream>>>(
        out1b, W2t, h2b, a_src2, a_dst2, asrc2, adst2, N);
    gat_agg1<<<(N + 3) / 4, 256, 0, stream>>>(h2b, rowstart, srcs, asrc2, adst2, b2,
                                              batch, cnt_i, out, N);
}

// Round 9
// 238.441 us; speedup vs baseline: 6.7301x; 1.0742x over previous
//
#include <hip/hip_runtime.h>
#include <cmath>

#define HID 64
typedef unsigned short ushort_t;
typedef __attribute__((ext_vector_type(8))) short bf16x8;
typedef __attribute__((ext_vector_type(4))) float f32x4;

__device__ inline ushort_t f2b(float f) {
    unsigned u = __float_as_uint(f);
    unsigned r = (u + 0x7fffu + ((u >> 16) & 1u)) >> 16;
    return (ushort_t)r;
}
__device__ inline float b2f(ushort_t b) { return __uint_as_float(((unsigned)b) << 16); }

// ---------------- fills ----------------

__global__ void fill_i32(int* __restrict__ p, int v, long n) {
    long i = (long)blockIdx.x * blockDim.x + threadIdx.x;
    long stride = (long)gridDim.x * blockDim.x;
    for (; i < n; i += stride) p[i] = v;
}

// ---------------- prep: transposes + zero d_out + batch hist + edge count ----------
// blocks [0,128): W1t; [128,384): W2t; 384: zero out; [385,385+NHB): batch hist;
// [385+NHB, 385+NHB+NCB): degree count.
__global__ __launch_bounds__(256) void prep_k(const float* __restrict__ W1,
                                              const float* __restrict__ W2,
                                              ushort_t* __restrict__ W1t,
                                              ushort_t* __restrict__ W2t,
                                              const int* __restrict__ batch,
                                              int* __restrict__ cnt_i,
                                              float* __restrict__ outp,
                                              const int* __restrict__ ei,
                                              int* __restrict__ deg,
                                              int N, int E, int NHB) {
    int b = blockIdx.x;
    int t = threadIdx.x;
    if (b < 128) {
        W1t[(size_t)t * 128 + b] = f2b(W1[(size_t)b * 256 + t]);
    } else if (b < 384) {
        int k = b - 128;
        if (t < 64) W2t[(size_t)t * 256 + k] = f2b(W2[(size_t)k * 64 + t]);
    } else if (b == 384) {
        int i = t * 8;
        #pragma unroll
        for (int j = 0; j < 8; ++j) outp[i + j] = 0.f;
    } else if (b < 385 + NHB) {
        __shared__ int lh[32];
        if (t < 32) lh[t] = 0;
        __syncthreads();
        int i = (b - 385) * 256 + t;
        if (i < N) atomicAdd(&lh[batch[i]], 1);
        __syncthreads();
        if (t < 32 && lh[t] > 0) atomicAdd(&cnt_i[t], lh[t]);
    } else {
        int e = (b - 385 - NHB) * 256 + t;
        int T = E + N;
        if (e < T) {
            int d = (e < E) ? ei[E + e] : (e - E);
            atomicAdd(&deg[d], 1);
        }
    }
}

// ---------------- CSR scan ----------------

__global__ __launch_bounds__(256) void scan1_k(const int* __restrict__ deg,
                                               int* __restrict__ bsum, int N) {
    int i = blockIdx.x * 256 + threadIdx.x;
    int v = (i < N) ? deg[i] : 0;
    #pragma unroll
    for (int off = 32; off > 0; off >>= 1) v += __shfl_xor(v, off, 64);
    __shared__ int ws[4];
    if ((threadIdx.x & 63) == 0) ws[threadIdx.x >> 6] = v;
    __syncthreads();
    if (threadIdx.x == 0) bsum[blockIdx.x] = ws[0] + ws[1] + ws[2] + ws[3];
}

__global__ __launch_bounds__(256) void scan3_k(const int* __restrict__ deg,
                                               const int* __restrict__ bsum,
                                               int* __restrict__ rowstart, int N, int NB) {
    int t = threadIdx.x;
    int lane = t & 63, wave = t >> 6;
    int pv = (t < NB && t < (int)blockIdx.x) ? bsum[t] : 0;
    #pragma unroll
    for (int off = 32; off > 0; off >>= 1) pv += __shfl_xor(pv, off, 64);
    __shared__ int wsp[4];
    if (lane == 0) wsp[wave] = pv;
    __syncthreads();
    int base = wsp[0] + wsp[1] + wsp[2] + wsp[3];

    int i = blockIdx.x * 256 + t;
    int v = (i < N) ? deg[i] : 0;
    int inc = v;
    #pragma unroll
    for (int off = 1; off < 64; off <<= 1) {
        int u = __shfl_up(inc, off, 64);
        if (lane >= off) inc += u;
    }
    __shared__ int wsum[4];
    if (lane == 63) wsum[wave] = inc;
    __syncthreads();
    int woff = base;
    for (int w = 0; w < wave; ++w) woff += wsum[w];
    int excl = inc - v + woff;
    if (i < N) rowstart[i] = excl;
    if (i == N - 1) rowstart[N] = excl + v;
}

// ---------------- mega: gemm1 (MFMA, fused alpha) + edge scatter ----------------
// blocks [0, NG1): 64-row GEMM tile; blocks [NG1, NG1+NS): scatter.
__global__ __launch_bounds__(256) void mega1_k(
        const float* __restrict__ x, const ushort_t* __restrict__ Bt,
        ushort_t* __restrict__ Cb, const float* __restrict__ a_src,
        const float* __restrict__ a_dst, float* __restrict__ os,
        float* __restrict__ od, int M, int NG1,
        const int* __restrict__ ei, int E, int N,
        const int* __restrict__ rowstart, int* __restrict__ cursor,
        int* __restrict__ srcs) {
    __shared__ ushort_t Alds[64][40];
    __shared__ ushort_t Blds[256][40];
    const int tid = threadIdx.x;

    if (blockIdx.x >= NG1) {
        // ---- scatter path ----
        int e = (blockIdx.x - NG1) * 256 + tid;
        int T = E + N;
        if (e < T) {
            int s, d;
            if (e < E) { s = ei[e]; d = ei[E + e]; } else { s = e - E; d = s; }
            int p = atomicAdd(&cursor[d], 1);
            srcs[rowstart[d] + p] = s;
        }
        return;
    }

    // ---- gemm1 path: WM=1, WN=4, K=128, f32 A fused-convert, AH=4 ----
    const int bm = blockIdx.x * 64;
    const int w = tid >> 6;
    const int l = tid & 63;
    const int lr = l >> 4;
    const int lc = l & 15;
    const int col0 = w * 64;

    f32x4 acc[4][4] = {};

    for (int kk = 0; kk < 4; ++kk) {
        __syncthreads();
        {
            int row = tid >> 2, part = tid & 3;   // 64 rows x 4 parts = 256
            int gm = bm + row;
            bf16x8 v = {0, 0, 0, 0, 0, 0, 0, 0};
            if (gm < M) {
                const float* ap = x + (size_t)gm * 128 + kk * 32 + part * 8;
                float4 v0 = *(const float4*)ap;
                float4 v1 = *(const float4*)(ap + 4);
                v[0] = (short)f2b(v0.x); v[1] = (short)f2b(v0.y);
                v[2] = (short)f2b(v0.z); v[3] = (short)f2b(v0.w);
                v[4] = (short)f2b(v1.x); v[5] = (short)f2b(v1.y);
                v[6] = (short)f2b(v1.z); v[7] = (short)f2b(v1.w);
            }
            *(bf16x8*)&Alds[row][part * 8] = v;
        }
        #pragma unroll
        for (int it = 0; it < 4; ++it) {
            int u = tid + it * 256;
            int col = u >> 2, part = u & 3;
            *(bf16x8*)&Blds[col][part * 8] =
                *(const bf16x8*)&Bt[(size_t)col * 128 + kk * 32 + part * 8];
        }
        __syncthreads();

        bf16x8 af[4], bfr[4];
        #pragma unroll
        for (int fr = 0; fr < 4; ++fr)
            af[fr] = *(const bf16x8*)&Alds[fr * 16 + lc][lr * 8];
        #pragma unroll
        for (int fc = 0; fc < 4; ++fc)
            bfr[fc] = *(const bf16x8*)&Blds[col0 + fc * 16 + lc][lr * 8];
        #pragma unroll
        for (int fr = 0; fr < 4; ++fr)
            #pragma unroll
            for (int fc = 0; fc < 4; ++fc)
                acc[fr][fc] = __builtin_amdgcn_mfma_f32_16x16x32_bf16(
                    af[fr], bfr[fc], acc[fr][fc], 0, 0, 0);
    }

    #pragma unroll
    for (int fr = 0; fr < 4; ++fr)
        #pragma unroll
        for (int r = 0; r < 4; ++r) {
            int gm = bm + fr * 16 + lr * 4 + r;
            if (gm >= M) continue;
            #pragma unroll
            for (int fc = 0; fc < 4; ++fc)
                Cb[(size_t)gm * 256 + col0 + fc * 16 + lc] = f2b(acc[fr][fc][r]);
        }

    {
        const int head = w;
        const float* __restrict__ asv = a_src + head * 64;
        const float* __restrict__ adv = a_dst + head * 64;
        #pragma unroll
        for (int fr = 0; fr < 4; ++fr)
            #pragma unroll
            for (int r = 0; r < 4; ++r) {
                float ps = 0.f, pd = 0.f;
                #pragma unroll
                for (int fc = 0; fc < 4; ++fc) {
                    float av = acc[fr][fc][r];
                    ps = fmaf(av, asv[fc * 16 + lc], ps);
                    pd = fmaf(av, adv[fc * 16 + lc], pd);
                }
                #pragma unroll
                for (int off = 1; off < 16; off <<= 1) {
                    ps += __shfl_xor(ps, off, 64);
                    pd += __shfl_xor(pd, off, 64);
                }
                int gm = bm + fr * 16 + lr * 4 + r;
                if (lc == 0 && gm < M) {
                    os[(size_t)gm * 4 + head] = ps;
                    od[(size_t)gm * 4 + head] = pd;
                }
            }
    }
}

// ---------------- MFMA GEMM (layer 2) with fused alpha epilogue ----------------
template<int WM, int WN, int K, bool B_WHOLE, int AH>
__global__ __launch_bounds__(WM * WN * 64) void gemm_mfma(
        const ushort_t* __restrict__ Ap, const ushort_t* __restrict__ Bt,
        ushort_t* __restrict__ Cb, const float* __restrict__ a_src,
        const float* __restrict__ a_dst, float* __restrict__ os,
        float* __restrict__ od, int M) {
    constexpr int T = WM * WN * 64;
    constexpr int BM = WM * 64;
    constexpr int BN = WN * 64;
    constexpr int BSTR = B_WHOLE ? (K + 8) : 40;

    __shared__ ushort_t Alds[BM][40];
    __shared__ ushort_t Blds[BN][BSTR];

    const int tid = threadIdx.x;
    const int bm = blockIdx.x * BM;
    const int w = tid >> 6;
    const int l = tid & 63;
    const int lr = l >> 4;
    const int lc = l & 15;
    const int row0 = (WM == 1) ? 0 : w * 64;
    const int col0 = (WN == 1) ? 0 : w * 64;

    f32x4 acc[4][4] = {};

    if (B_WHOLE) {
        constexpr int UPR = K / 8;
        for (int u = tid; u < BN * UPR; u += T) {
            int row = u / UPR, j = u % UPR;
            *(bf16x8*)&Blds[row][j * 8] = *(const bf16x8*)&Bt[(size_t)row * K + j * 8];
        }
    }

    for (int kk = 0; kk < K / 32; ++kk) {
        __syncthreads();
        for (int u = tid; u < BM * 4; u += T) {
            int row = u >> 2, part = u & 3;
            int gm = bm + row;
            bf16x8 v = {0, 0, 0, 0, 0, 0, 0, 0};
            if (gm < M)
                v = *(const bf16x8*)(Ap + (size_t)gm * K + kk * 32 + part * 8);
            *(bf16x8*)&Alds[row][part * 8] = v;
        }
        if (!B_WHOLE) {
            for (int u = tid; u < BN * 4; u += T) {
                int col = u >> 2, part = u & 3;
                *(bf16x8*)&Blds[col][part * 8] =
                    *(const bf16x8*)&Bt[(size_t)col * K + kk * 32 + part * 8];
            }
        }
        __syncthreads();

        const int koff = B_WHOLE ? kk * 32 : 0;
        bf16x8 af[4], bfr[4];
        #pragma unroll
        for (int fr = 0; fr < 4; ++fr)
            af[fr] = *(const bf16x8*)&Alds[row0 + fr * 16 + lc][lr * 8];
        #pragma unroll
        for (int fc = 0; fc < 4; ++fc)
            bfr[fc] = *(const bf16x8*)&Blds[col0 + fc * 16 + lc][koff + lr * 8];
        #pragma unroll
        for (int fr = 0; fr < 4; ++fr)
            #pragma unroll
            for (int fc = 0; fc < 4; ++fc)
                acc[fr][fc] = __builtin_amdgcn_mfma_f32_16x16x32_bf16(
                    af[fr], bfr[fc], acc[fr][fc], 0, 0, 0);
    }

    #pragma unroll
    for (int fr = 0; fr < 4; ++fr)
        #pragma unroll
        for (int r = 0; r < 4; ++r) {
            int gm = bm + row0 + fr * 16 + lr * 4 + r;
            if (gm >= M) continue;
            #pragma unroll
            for (int fc = 0; fc < 4; ++fc)
                Cb[(size_t)gm * BN + col0 + fc * 16 + lc] = f2b(acc[fr][fc][r]);
        }

    if (AH > 0) {
        const int head = (WN > 1) ? w : 0;
        const float* __restrict__ asv = a_src + head * 64;
        const float* __restrict__ adv = a_dst + head * 64;
        #pragma unroll
        for (int fr = 0; fr < 4; ++fr)
            #pragma unroll
            for (int r = 0; r < 4; ++r) {
                float ps = 0.f, pd = 0.f;
                #pragma unroll
                for (int fc = 0; fc < 4; ++fc) {
                    float av = acc[fr][fc][r];
                    ps = fmaf(av, asv[fc * 16 + lc], ps);
                    pd = fmaf(av, adv[fc * 16 + lc], pd);
                }
                #pragma unroll
                for (int off = 1; off < 16; off <<= 1) {
                    ps += __shfl_xor(ps, off, 64);
                    pd += __shfl_xor(pd, off, 64);
                }
                int gm = bm + row0 + fr * 16 + lr * 4 + r;
                if (lc == 0 && gm < M) {
                    os[(size_t)gm * AH + head] = ps;
                    od[(size_t)gm * AH + head] = pd;
                }
            }
    }
}

// ---------------- GAT aggregation, H=4: one wave per destination ----------------
#define MAXD 128
__global__ __launch_bounds__(256) void gat_agg4(const ushort_t* __restrict__ hb,
        const int* __restrict__ rowstart, const int* __restrict__ srcs,
        const float* __restrict__ as, const float* __restrict__ ad,
        const float* __restrict__ bias, ushort_t* __restrict__ outb, int N) {
    __shared__ int ssrc_s[4][MAXD];
    __shared__ float sw_s[4][MAXD][4];
    __shared__ float hstat_s[4][2][4];
    const int wave = threadIdx.x >> 6;
    const int lane = threadIdx.x & 63;
    int d = blockIdx.x * 4 + wave;
    if (d >= N) return;
    int* ssrc = ssrc_s[wave];
    float (*sw)[4] = sw_s[wave];
    int beg = rowstart[d];
    int deg = rowstart[d + 1] - beg;
    int dcap = deg < MAXD ? deg : MAXD;
    for (int i = lane; i < dcap; i += 64) ssrc[i] = srcs[beg + i];

    const int isub = lane >> 2;
    const int hd = lane & 3;
    float adv = ad[d * 4 + hd];
    float vmax = -INFINITY;
    for (int e0 = 0; e0 < deg; e0 += 16) {
        int e = e0 + isub;
        if (e < deg) {
            int s = (e < MAXD) ? ssrc[e] : srcs[beg + e];
            float v = as[s * 4 + hd] + adv;
            v = v > 0.f ? v : 0.2f * v;
            if (e < MAXD) sw[e][hd] = v;
            vmax = fmaxf(vmax, v);
        }
    }
    #pragma unroll
    for (int off = 4; off < 64; off <<= 1) vmax = fmaxf(vmax, __shfl_xor(vmax, off, 64));
    float dsum = 0.f;
    for (int e0 = 0; e0 < deg; e0 += 16) {
        int e = e0 + isub;
        if (e < deg) {
            float v;
            if (e < MAXD) v = sw[e][hd];
            else {
                int s = srcs[beg + e];
                v = as[s * 4 + hd] + adv;
                v = v > 0.f ? v : 0.2f * v;
            }
            float ex = __expf(v - vmax);
            if (e < MAXD) sw[e][hd] = ex;
            dsum += ex;
        }
    }
    #pragma unroll
    for (int off = 4; off < 64; off <<= 1) dsum += __shfl_xor(dsum, off, 64);
    float rden = 1.f / (dsum + 1e-16f);
    for (int e0 = 0; e0 < dcap; e0 += 16) {
        int e = e0 + isub;
        if (e < dcap) sw[e][hd] *= rden;
    }
    if (deg > MAXD && isub == 0) {
        hstat_s[wave][0][hd] = vmax;
        hstat_s[wave][1][hd] = rden;
    }

    const int hd2 = lane >> 4;
    const ushort_t* __restrict__ hrow = hb + (size_t)(lane * 4);
    float a0 = 0.f, a1 = 0.f, a2 = 0.f, a3 = 0.f;
    int e = 0;
    for (; e + 4 <= dcap; e += 4) {
        int s0 = __builtin_amdgcn_readfirstlane(ssrc[e]);
        int s1 = __builtin_amdgcn_readfirstlane(ssrc[e + 1]);
        int s2 = __builtin_amdgcn_readfirstlane(ssrc[e + 2]);
        int s3 = __builtin_amdgcn_readfirstlane(ssrc[e + 3]);
        ushort4 g0 = *(const ushort4*)(hrow + (size_t)s0 * 256);
        ushort4 g1 = *(const ushort4*)(hrow + (size_t)s1 * 256);
        ushort4 g2 = *(const ushort4*)(hrow + (size_t)s2 * 256);
        ushort4 g3 = *(const ushort4*)(hrow + (size_t)s3 * 256);
        float w0 = sw[e][hd2], w1 = sw[e + 1][hd2];
        float w2 = sw[e + 2][hd2], w3 = sw[e + 3][hd2];
        a0 = fmaf(b2f(g0.x), w0, a0); a1 = fmaf(b2f(g0.y), w0, a1);
        a2 = fmaf(b2f(g0.z), w0, a2); a3 = fmaf(b2f(g0.w), w0, a3);
        a0 = fmaf(b2f(g1.x), w1, a0); a1 = fmaf(b2f(g1.y), w1, a1);
        a2 = fmaf(b2f(g1.z), w1, a2); a3 = fmaf(b2f(g1.w), w1, a3);
        a0 = fmaf(b2f(g2.x), w2, a0); a1 = fmaf(b2f(g2.y), w2, a1);
        a2 = fmaf(b2f(g2.z), w2, a2); a3 = fmaf(b2f(g2.w), w2, a3);
        a0 = fmaf(b2f(g3.x), w3, a0); a1 = fmaf(b2f(g3.y), w3, a1);
        a2 = fmaf(b2f(g3.z), w3, a2); a3 = fmaf(b2f(g3.w), w3, a3);
    }
    for (; e < dcap; ++e) {
        int s = __builtin_amdgcn_readfirstlane(ssrc[e]);
        float w = sw[e][hd2];
        ushort4 g = *(const ushort4*)(hrow + (size_t)s * 256);
        a0 = fmaf(b2f(g.x), w, a0); a1 = fmaf(b2f(g.y), w, a1);
        a2 = fmaf(b2f(g.z), w, a2); a3 = fmaf(b2f(g.w), w, a3);
    }
    if (deg > MAXD) {
        float vm2 = hstat_s[wave][0][hd2];
        float rd2 = hstat_s[wave][1][hd2];
        float adv2 = ad[d * 4 + hd2];
        for (int j = MAXD; j < deg; ++j) {
            int s = srcs[beg + j];
            float v = as[s * 4 + hd2] + adv2;
            v = v > 0.f ? v : 0.2f * v;
            float w = __expf(v - vm2) * rd2;
            ushort4 g = *(const ushort4*)(hrow + (size_t)s * 256);
            a0 = fmaf(b2f(g.x), w, a0); a1 = fmaf(b2f(g.y), w, a1);
            a2 = fmaf(b2f(g.z), w, a2); a3 = fmaf(b2f(g.w), w, a3);
        }
    }
    int cb = lane * 4;
    ushort4 ov;
    ov.x = f2b(fmaxf(a0 + bias[cb + 0], 0.f));
    ov.y = f2b(fmaxf(a1 + bias[cb + 1], 0.f));
    ov.z = f2b(fmaxf(a2 + bias[cb + 2], 0.f));
    ov.w = f2b(fmaxf(a3 + bias[cb + 3], 0.f));
    *(ushort4*)&outb[(size_t)d * 256 + cb] = ov;
}

// ---------------- GAT aggregation H=1 with fused mean-pool into d_out ----------
__global__ __launch_bounds__(256) void gat_agg1(const ushort_t* __restrict__ hb,
        const int* __restrict__ rowstart, const int* __restrict__ srcs,
        const float* __restrict__ as, const float* __restrict__ ad,
        const float* __restrict__ bias, const int* __restrict__ batch,
        const int* __restrict__ cnt_i, float* __restrict__ outp, int N) {
    __shared__ int ssrc_s[4][MAXD];
    __shared__ float sw_s[4][MAXD];
    __shared__ float prow[4][64];
    __shared__ int gws[4];
    const int wave = threadIdx.x >> 6;
    const int lane = threadIdx.x & 63;
    int d = blockIdx.x * 4 + wave;
    bool active = d < N;
    if (active) {
        int* ssrc = ssrc_s[wave];
        float* sw = sw_s[wave];
        int beg = rowstart[d];
        int deg = rowstart[d + 1] - beg;
        int dcap = deg < MAXD ? deg : MAXD;
        for (int i = lane; i < dcap; i += 64) ssrc[i] = srcs[beg + i];

        float adv = ad[d];
        float vmax = -INFINITY;
        for (int e0 = 0; e0 < deg; e0 += 64) {
            int e = e0 + lane;
            if (e < deg) {
                int s = (e < MAXD) ? ssrc[e] : srcs[beg + e];
                float v = as[s] + adv;
                v = v > 0.f ? v : 0.2f * v;
                if (e < MAXD) sw[e] = v;
                vmax = fmaxf(vmax, v);
            }
        }
        #pragma unroll
        for (int off = 1; off < 64; off <<= 1) vmax = fmaxf(vmax, __shfl_xor(vmax, off, 64));
        float dsum = 0.f;
        for (int e0 = 0; e0 < deg; e0 += 64) {
            int e = e0 + lane;
            if (e < deg) {
                float v;
                if (e < MAXD) v = sw[e];
                else {
                    int s = srcs[beg + e];
                    v = as[s] + adv;
                    v = v > 0.f ? v : 0.2f * v;
                }
                float ex = __expf(v - vmax);
                if (e < MAXD) sw[e] = ex;
                dsum += ex;
            }
        }
        #pragma unroll
        for (int off = 1; off < 64; off <<= 1) dsum += __shfl_xor(dsum, off, 64);
        float rden = 1.f / (dsum + 1e-16f);
        for (int e0 = 0; e0 < dcap; e0 += 64) {
            int e = e0 + lane;
            if (e < dcap) sw[e] *= rden;
        }

        const int esub = lane >> 4;
        const int cg = lane & 15;
        const ushort_t* __restrict__ hrow = hb + (size_t)(cg * 4);
        float a0 = 0.f, a1 = 0.f, a2 = 0.f, a3 = 0.f;
        int e0 = 0;
        for (; e0 + 8 <= dcap; e0 += 8) {
            int eA = e0 + esub, eB = e0 + esub + 4;
            int sA = ssrc[eA], sB = ssrc[eB];
            float wA = sw[eA], wB = sw[eB];
            ushort4 gA = *(const ushort4*)(hrow + (size_t)sA * 64);
            ushort4 gB = *(const ushort4*)(hrow + (size_t)sB * 64);
            a0 = fmaf(b2f(gA.x), wA, a0); a1 = fmaf(b2f(gA.y), wA, a1);
            a2 = fmaf(b2f(gA.z), wA, a2); a3 = fmaf(b2f(gA.w), wA, a3);
            a0 = fmaf(b2f(gB.x), wB, a0); a1 = fmaf(b2f(gB.y), wB, a1);
            a2 = fmaf(b2f(gB.z), wB, a2); a3 = fmaf(b2f(gB.w), wB, a3);
        }
        for (; e0 < dcap; e0 += 4) {
            int e = e0 + esub;
            if (e < dcap) {
                int s = ssrc[e];
                float w = sw[e];
                ushort4 g = *(const ushort4*)(hrow + (size_t)s * 64);
                a0 = fmaf(b2f(g.x), w, a0); a1 = fmaf(b2f(g.y), w, a1);
                a2 = fmaf(b2f(g.z), w, a2); a3 = fmaf(b2f(g.w), w, a3);
            }
        }
        for (int j = MAXD + esub; j < deg; j += 4) {
            int s = srcs[beg + j];
            float v = as[s] + adv;
            v = v > 0.f ? v : 0.2f * v;
            float w = __expf(v - vmax) * rden;
            ushort4 g = *(const ushort4*)(hrow + (size_t)s * 64);
            a0 = fmaf(b2f(g.x), w, a0); a1 = fmaf(b2f(g.y), w, a1);
            a2 = fmaf(b2f(g.z), w, a2); a3 = fmaf(b2f(g.w), w, a3);
        }
        a0 += __shfl_xor(a0, 16, 64); a0 += __shfl_xor(a0, 32, 64);
        a1 += __shfl_xor(a1, 16, 64); a1 += __shfl_xor(a1, 32, 64);
        a2 += __shfl_xor(a2, 16, 64); a2 += __shfl_xor(a2, 32, 64);
        a3 += __shfl_xor(a3, 16, 64); a3 += __shfl_xor(a3, 32, 64);
        int g = batch[d];
        if (esub == 0) {
            float cntf = fmaxf((float)cnt_i[g], 1.f);
            float rc = 1.f / cntf;
            int cb = cg * 4;
            float4 o;
            o.x = (a0 + bias[cb + 0]) * rc;
            o.y = (a1 + bias[cb + 1]) * rc;
            o.z = (a2 + bias[cb + 2]) * rc;
            o.w = (a3 + bias[cb + 3]) * rc;
            *(float4*)&prow[wave][cb] = o;
        }
        if (lane == 0) gws[wave] = g;
    } else {
        if (lane == 0) gws[wave] = -1;
    }
    __syncthreads();
    if (threadIdx.x < 64) {
        int t = threadIdx.x;
        int g0 = gws[0];
        if (g0 >= 0 && gws[1] == g0 && gws[2] == g0 && gws[3] == g0) {
            atomicAdd(&outp[g0 * 64 + t],
                      prow[0][t] + prow[1][t] + prow[2][t] + prow[3][t]);
        } else {
            #pragma unroll
            for (int w2 = 0; w2 < 4; ++w2)
                if (gws[w2] >= 0) atomicAdd(&outp[gws[w2] * 64 + t], prow[w2][t]);
        }
    }
}

// ---------------- launch ----------------

extern "C" void kernel_launch(void* const* d_in, const int* in_sizes, int n_in,
                              void* d_out, int out_size, void* d_ws, size_t ws_size,
                              hipStream_t stream) {
    const float* x      = (const float*)d_in[0];
    const int*   ei     = (const int*)d_in[1];
    const int*   batch  = (const int*)d_in[2];
    const float* W1     = (const float*)d_in[3];
    const float* a_src1 = (const float*)d_in[4];
    const float* a_dst1 = (const float*)d_in[5];
    const float* b1     = (const float*)d_in[6];
    const float* W2     = (const float*)d_in[7];
    const float* a_src2 = (const float*)d_in[8];
    const float* a_dst2 = (const float*)d_in[9];
    const float* b2     = (const float*)d_in[10];
    float* out = (float*)d_out;

    const int N = in_sizes[0] / 128;    // 50000
    const int E = in_sizes[1] / 2;      // 800000
    const int F1 = 256;
    const int F2 = 64;
    const int T = E + N;
    const int NB = (N + 255) / 256;     // scan/hist blocks (196)
    const int NCB = (T + 255) / 256;    // count/scatter blocks (3321)
    const int NG1 = (N + 63) / 64;      // gemm1 blocks (782)

    // ---- workspace layout (float units) ----
    float* ws = (float*)d_ws;
    size_t o = 0;
    ushort_t* h1b   = (ushort_t*)(ws + o); o += (size_t)N * F1 / 2;
    ushort_t* out1b = (ushort_t*)(ws + o); o += (size_t)N * F1 / 2;
    ushort_t* h2b   = (ushort_t*)(ws + o); o += (size_t)N * F2 / 2;
    float* asrc1 = ws + o; o += (size_t)N * 4;
    float* adst1 = ws + o; o += (size_t)N * 4;
    float* asrc2 = ws + o; o += (size_t)N;
    float* adst2 = ws + o; o += (size_t)N;
    ushort_t* W1t = (ushort_t*)(ws + o); o += 256 * 128 / 2;
    ushort_t* W2t = (ushort_t*)(ws + o); o += 64 * 256 / 2;
    int* ib = (int*)(ws + o);
    size_t io = 0;
    int* deg      = ib + io; io += N;      // deg+cursor+cnt contiguous -> one fill
    int* cursor   = ib + io; io += N;
    int* cnt_i    = ib + io; io += 32;
    int* rowstart = ib + io; io += N + 1;
    int* bsum     = ib + io; io += NB;
    int* srcs     = ib + io; io += T;
    (void)ws_size; (void)n_in; (void)out_size;

    // ---- zero counters; prep (transposes + hist + zero out + degree count) ----
    fill_i32<<<256, 256, 0, stream>>>(deg, 0, 2L * N + 32);
    prep_k<<<385 + NB + NCB, 256, 0, stream>>>(W1, W2, W1t, W2t, batch, cnt_i, out,
                                               ei, deg, N, E, NB);

    // ---- CSR scan ----
    scan1_k<<<NB, 256, 0, stream>>>(deg, bsum, N);
    scan3_k<<<NB, 256, 0, stream>>>(deg, bsum, rowstart, N, NB);

    // ---- gemm1 + scatter in one dispatch ----
    mega1_k<<<NG1 + NCB, 256, 0, stream>>>(x, W1t, h1b, a_src1, a_dst1,
                                           asrc1, adst1, N, NG1,
                                           ei, E, N, rowstart, cursor, srcs);

    // ---- layer 1 aggregation ----
    gat_agg4<<<(N + 3) / 4, 256, 0, stream>>>(h1b, rowstart, srcs, asrc1, adst1, b1, out1b, N);

    // ---- layer 2 (+ fused mean pool) ----
    gemm_mfma<2, 1, 256, true, 1><<<(N + 127) / 128, 128, 0, stream>>>(
        out1b, W2t, h2b, a_src2, a_dst2, asrc2, adst2, N);
    gat_agg1<<<(N + 3) / 4, 256, 0, stream>>>(h2b, rowstart, srcs, asrc2, adst2, b2,
                                              batch, cnt_i, out, N);
}